// Round 3
// baseline (1241.530 us; speedup 1.0000x reference)
//
#include <hip/hip_runtime.h>

// ---------------------------------------------------------------------------
// QAttn (I-BERT style int8 fake-quant attention), B=64 N=197 C=768 H=12 D=64
// Flash-style restructure to fit ws <= ~158 MB (round-1's 277 MB likely
// overran ws_size -> GPU fault). No attn matrix materialization:
//   1 k_init        slots
//   2 k_wquant      per-row int8 weight fake-quant -> wq1, wq2
//   3 k_gemm_nt<false,1>  qkv = x @ wq1^T + b   (+fused per-slice min/max)
//   4 k_dequant_qkv in-place double fake-quant (global fq then slice fq)
//   5 k_qk_rowmax   scores global min/max (atomics) + per-row raw max
//   6 k_attn_pv     recompute scores, int-softmax e, out=(e.V)/(sum e)
//                   (+fused out min/max)
//   7 k_gemm_nt<true,2>   out2 = fq(out) @ wq2^T + b (+fused min/max)
//   8 k_fq_inplace  final fake-quant of d_out
// Numerics: rintf == jnp.round (half-even); f64-folded b/a, 1/a constants;
// scalbnf == *exp2(-int) exactly; integer-valued f32 polynomial is
// contraction-safe. Workspace: 157.3 MB.
// ---------------------------------------------------------------------------

#define NB 64
#define NN 197
#define NC 768
#define NH 12
#define ND 64
#define NO3 2304
#define NBH (NB*NH)      // 768
#define NM (NB*NN)       // 12608

typedef unsigned int u32;

__device__ __forceinline__ u32 fenc(float f){
  u32 u = __float_as_uint(f);
  return (u & 0x80000000u) ? ~u : (u | 0x80000000u);
}
__device__ __forceinline__ float fdec(u32 e){
  return (e & 0x80000000u) ? __uint_as_float(e ^ 0x80000000u) : __uint_as_float(~e);
}
__device__ __forceinline__ float wmin(float v){
#pragma unroll
  for (int o=32;o>0;o>>=1) v = fminf(v, __shfl_xor(v,o,64));
  return v;
}
__device__ __forceinline__ float wmax(float v){
#pragma unroll
  for (int o=32;o>0;o>>=1) v = fmaxf(v, __shfl_xor(v,o,64));
  return v;
}
__device__ __forceinline__ float fqdq(float x, float s, float z){
  float q = rintf(x/s) + z;
  q = fminf(fmaxf(q, 0.f), 255.f);
  return (q - z) * s;
}

// slots[12]: {q_mn,mx, k_mn,mx, v_mn,mx, attn_mn,mx, out_mn,mx, out2_mn,mx}
__global__ void k_init(u32* slots){
  int t = threadIdx.x;
  if (t < 12) slots[t] = (t & 1) ? 0u : 0xFFFFFFFFu;
}

__global__ __launch_bounds__(256) void k_wquant(const float* __restrict__ wqkv,
    const float* __restrict__ wproj, float* __restrict__ wq1, float* __restrict__ wq2){
  int row = blockIdx.x;
  const float* src; float* dst;
  if (row < NO3){ src = wqkv + (size_t)row*NC; dst = wq1 + (size_t)row*NC; }
  else { int r2 = row - NO3; src = wproj + (size_t)r2*NC; dst = wq2 + (size_t)r2*NC; }
  int t = threadIdx.x;
  float w0 = src[t], w1 = src[t+256], w2 = src[t+512];
  float am = fmaxf(fabsf(w0), fmaxf(fabsf(w1), fabsf(w2)));
  __shared__ float red[4];
  am = wmax(am);
  if ((t&63)==0) red[t>>6] = am;
  __syncthreads();
  am = fmaxf(fmaxf(red[0],red[1]), fmaxf(red[2],red[3]));
  float s = fmaxf(am / 127.0f, 1e-8f);
  dst[t]     = fminf(fmaxf(rintf(w0/s), -128.f), 127.f) * s;
  dst[t+256] = fminf(fmaxf(rintf(w1/s), -128.f), 127.f) * s;
  dst[t+512] = fminf(fmaxf(rintf(w2/s), -128.f), 127.f) * s;
}

// C[m,o] = A[m,:].W[o,:] + bias[o]; 64x256 tile, 8x8/thread.
// RMODE 1: fused min/max -> oslot[2*(o0/768)] pairs (qkv slices)
// RMODE 2: fused min/max -> oslot[0,1]
template<bool AQ, int RMODE>
__global__ __launch_bounds__(256) void k_gemm_nt(const float* __restrict__ A,
    const float* __restrict__ W, const float* __restrict__ bias, float* __restrict__ C,
    int K, int O, const u32* __restrict__ qslot, u32* oslot){
  __shared__ float As[16][64];
  __shared__ float Bs[16][256];
  __shared__ float redn[4], redx[4];
  float sA = 1.f, zA = 0.f;
  if constexpr (AQ){
    float mn = fdec(qslot[0]), mx = fdec(qslot[1]);
    sA = fmaxf((mx-mn)/255.0f, 1e-8f);
    zA = rintf(-mn/sA);
  }
  int tid = threadIdx.x;
  long m0 = (long)blockIdx.y*64;
  long o0 = (long)blockIdx.x*256;
  int r = tid>>2, c4 = (tid&3)<<2;
  int ty = tid>>5;
  int tx = tid&31;
  const float* Ap = A + (m0+r)*K + c4;
  const float* Wp = W + (o0+r)*K + c4;
  float acc[8][8] = {};
  for (int kk=0; kk<K; kk+=16){
    float4 a0 = *(const float4*)(Ap+kk);
    float4 b0 = *(const float4*)(Wp+kk);
    float4 b1 = *(const float4*)(Wp+(long)64*K+kk);
    float4 b2 = *(const float4*)(Wp+(long)128*K+kk);
    float4 b3 = *(const float4*)(Wp+(long)192*K+kk);
    if constexpr (AQ){
      a0.x=fqdq(a0.x,sA,zA); a0.y=fqdq(a0.y,sA,zA);
      a0.z=fqdq(a0.z,sA,zA); a0.w=fqdq(a0.w,sA,zA);
    }
    __syncthreads();
    As[c4+0][r]=a0.x; As[c4+1][r]=a0.y; As[c4+2][r]=a0.z; As[c4+3][r]=a0.w;
    Bs[c4+0][r    ]=b0.x; Bs[c4+1][r    ]=b0.y; Bs[c4+2][r    ]=b0.z; Bs[c4+3][r    ]=b0.w;
    Bs[c4+0][r+64 ]=b1.x; Bs[c4+1][r+64 ]=b1.y; Bs[c4+2][r+64 ]=b1.z; Bs[c4+3][r+64 ]=b1.w;
    Bs[c4+0][r+128]=b2.x; Bs[c4+1][r+128]=b2.y; Bs[c4+2][r+128]=b2.z; Bs[c4+3][r+128]=b2.w;
    Bs[c4+0][r+192]=b3.x; Bs[c4+1][r+192]=b3.y; Bs[c4+2][r+192]=b3.z; Bs[c4+3][r+192]=b3.w;
    __syncthreads();
#pragma unroll
    for (int k=0;k<16;k++){
      float av[8], bv[8];
      *(float4*)&av[0] = *(const float4*)&As[k][ty*8];
      *(float4*)&av[4] = *(const float4*)&As[k][ty*8+4];
      *(float4*)&bv[0] = *(const float4*)&Bs[k][tx*4];
      *(float4*)&bv[4] = *(const float4*)&Bs[k][128+tx*4];
#pragma unroll
      for (int i=0;i<8;i++)
#pragma unroll
        for (int j=0;j<8;j++) acc[i][j] = fmaf(av[i], bv[j], acc[i][j]);
    }
  }
  float cmn = 3.4e38f, cmx = -3.4e38f;
#pragma unroll
  for (int i=0;i<8;i++){
    long mrow = m0 + ty*8 + i;
    float* Cr = C + mrow*O + o0;
#pragma unroll
    for (int j=0;j<4;j++){
      float c0 = acc[i][j]   + bias[o0 + tx*4 + j];
      float c1 = acc[i][j+4] + bias[o0 + 128 + tx*4 + j];
      Cr[tx*4+j]     = c0;
      Cr[128+tx*4+j] = c1;
      if constexpr (RMODE > 0){
        cmn = fminf(cmn, fminf(c0,c1));
        cmx = fmaxf(cmx, fmaxf(c0,c1));
      }
    }
  }
  if constexpr (RMODE > 0){
    cmn = wmin(cmn); cmx = wmax(cmx);
    int wv = tid>>6;
    if ((tid&63)==0){ redn[wv]=cmn; redx[wv]=cmx; }
    __syncthreads();
    if (tid==0){
      float mn = fminf(fminf(redn[0],redn[1]), fminf(redn[2],redn[3]));
      float mx = fmaxf(fmaxf(redx[0],redx[1]), fmaxf(redx[2],redx[3]));
      int sb = (RMODE==1) ? 2*(int)(blockIdx.x/3) : 0;   // o0/768
      atomicMin(&oslot[sb],   fenc(mn));
      atomicMax(&oslot[sb+1], fenc(mx));
    }
  }
}

// in-place: qkv -> slice_fq(global_fq(qkv)); slice ranges via monotonicity.
__global__ __launch_bounds__(256) void k_dequant_qkv(float* qkv, const u32* __restrict__ slots){
  float mnr0=fdec(slots[0]), mxr0=fdec(slots[1]);
  float mnr1=fdec(slots[2]), mxr1=fdec(slots[3]);
  float mnr2=fdec(slots[4]), mxr2=fdec(slots[5]);
  float mn1 = fminf(mnr0, fminf(mnr1, mnr2));
  float mx1 = fmaxf(mxr0, fmaxf(mxr1, mxr2));
  float s1 = fmaxf((mx1-mn1)/255.0f, 1e-8f);
  float z1 = rintf(-mn1/s1);
  float a0 = fqdq(mnr0,s1,z1), b0 = fqdq(mxr0,s1,z1);
  float a1 = fqdq(mnr1,s1,z1), b1 = fqdq(mxr1,s1,z1);
  float a2 = fqdq(mnr2,s1,z1), b2 = fqdq(mxr2,s1,z1);
  float s20 = fmaxf((b0-a0)/255.0f, 1e-8f), z20 = rintf(-a0/s20);
  float s21 = fmaxf((b1-a1)/255.0f, 1e-8f), z21 = rintf(-a1/s21);
  float s22 = fmaxf((b2-a2)/255.0f, 1e-8f), z22 = rintf(-a2/s22);
  const long n4 = (long)NM*NO3/4;
  for (long i = (long)blockIdx.x*blockDim.x + threadIdx.x; i < n4; i += (long)gridDim.x*blockDim.x){
    float4 v = ((float4*)qkv)[i];
    int sl = (int)((i*4) % NO3) / NC;
    float s2, z2;
    if (sl==0){ s2=s20; z2=z20; } else if (sl==1){ s2=s21; z2=z21; } else { s2=s22; z2=z22; }
    v.x = fqdq(fqdq(v.x,s1,z1), s2, z2);
    v.y = fqdq(fqdq(v.y,s1,z1), s2, z2);
    v.z = fqdq(fqdq(v.z,s1,z1), s2, z2);
    v.w = fqdq(fqdq(v.w,s1,z1), s2, z2);
    ((float4*)qkv)[i] = v;
  }
}

// Pass 1: raw-score global min/max (slots 6,7) + per-row raw max
__global__ __launch_bounds__(256) void k_qk_rowmax(const float* __restrict__ qkv,
    float* __restrict__ rowmax, u32* slots){
  __shared__ float Qs[16][64];
  __shared__ float Ks[16][64];
  __shared__ float redn[4], redx[4];
  int bh = blockIdx.y; int b = bh/NH, h = bh - b*NH;
  int nt = blockIdx.x;
  const float* qb = qkv + (size_t)b*NN*NO3 + h*ND;
  const float* kb = qb + NC;
  int tid = threadIdx.x;
  int r = tid>>2, c4 = (tid&3)<<2;
  int ty = tid>>4, tx = tid&15;
  int qrow = nt*64 + r;
  bool qv = qrow < NN;
  const float* Ap = qb + (size_t)qrow*NO3 + c4;
  float rmax[4] = {-3.4e38f,-3.4e38f,-3.4e38f,-3.4e38f};
  float gmn = 3.4e38f, gmx = -3.4e38f;
  for (int mt=0; mt<4; mt++){
    int krow = mt*64 + r;
    bool kv = krow < NN;
    const float* Bp = kb + (size_t)krow*NO3 + c4;
    float acc[4][4] = {};
    for (int kk=0; kk<ND; kk+=16){
      float4 a  = qv ? *(const float4*)(Ap+kk) : make_float4(0.f,0.f,0.f,0.f);
      float4 bb = kv ? *(const float4*)(Bp+kk) : make_float4(0.f,0.f,0.f,0.f);
      __syncthreads();
      Qs[c4+0][r]=a.x;  Qs[c4+1][r]=a.y;  Qs[c4+2][r]=a.z;  Qs[c4+3][r]=a.w;
      Ks[c4+0][r]=bb.x; Ks[c4+1][r]=bb.y; Ks[c4+2][r]=bb.z; Ks[c4+3][r]=bb.w;
      __syncthreads();
#pragma unroll
      for (int k=0;k<16;k++){
        float av[4], bv[4];
        *(float4*)av = *(const float4*)&Qs[k][ty<<2];
        *(float4*)bv = *(const float4*)&Ks[k][tx<<2];
#pragma unroll
        for (int i=0;i<4;i++)
#pragma unroll
          for (int j=0;j<4;j++) acc[i][j] = fmaf(av[i], bv[j], acc[i][j]);
      }
    }
#pragma unroll
    for (int i=0;i<4;i++){
      int n = nt*64 + (ty<<2) + i;
      if (n < NN){
#pragma unroll
        for (int j=0;j<4;j++){
          int m = mt*64 + (tx<<2) + j;
          if (m < NN){
            float sc = acc[i][j]*0.125f;
            rmax[i] = fmaxf(rmax[i], sc);
            gmn = fminf(gmn, sc); gmx = fmaxf(gmx, sc);
          }
        }
      }
    }
  }
#pragma unroll
  for (int i=0;i<4;i++){
    float v = rmax[i];
#pragma unroll
    for (int o=1;o<16;o<<=1) v = fmaxf(v, __shfl_xor(v,o,64));
    rmax[i] = v;
  }
  if (tx==0){
#pragma unroll
    for (int i=0;i<4;i++){
      int n = nt*64 + (ty<<2) + i;
      if (n < NN) rowmax[(size_t)bh*NN + n] = rmax[i];
    }
  }
  gmn = wmin(gmn); gmx = wmax(gmx);
  int wv = tid>>6;
  if ((tid&63)==0){ redn[wv]=gmn; redx[wv]=gmx; }
  __syncthreads();
  if (tid==0){
    float mn = fminf(fminf(redn[0],redn[1]), fminf(redn[2],redn[3]));
    float mx = fmaxf(fmaxf(redx[0],redx[1]), fmaxf(redx[2],redx[3]));
    atomicMin(&slots[6], fenc(mn));
    atomicMax(&slots[7], fenc(mx));
  }
}

// Pass 2: recompute scores, I-BERT exp, out = (e.V)/(sum e); fused out min/max
__global__ __launch_bounds__(256) void k_attn_pv(const float* __restrict__ qkv,
    const float* __restrict__ rowmax, const u32* __restrict__ slots,
    float* __restrict__ outp, u32* oslot){
  __shared__ float Qs[16][64];
  __shared__ float Ks[16][64];
  __shared__ float Es[64][68];
  __shared__ float Vs[64][68];
  __shared__ float redn[4], redx[4];
  float mnA = fdec(slots[6]), mxA = fdec(slots[7]);
  float s = fmaxf((mxA-mnA)/255.0f, 1e-8f);
  float z = rintf(-mnA/s);
  float x0 = floorf(-0.6931471805599453f / s);
  float ba = (float)(0.96963238/0.35815147);
  float ca = (float)(1.0/0.35815147);
  float bint = floorf(ba/s);
  float cint = floorf(ca/(s*s));
  float as2 = (0.35815147f*s)*s;
  float x030 = 30.f*x0;
  int bh = blockIdx.y; int b = bh/NH, h = bh - b*NH;
  int nt = blockIdx.x;
  const float* qb = qkv + (size_t)b*NN*NO3 + h*ND;
  const float* kb = qb + NC;
  const float* vb = qkv + (size_t)b*NN*NO3 + 2*NC + h*ND;
  int tid = threadIdx.x;
  int r = tid>>2, c4 = (tid&3)<<2;
  int ty = tid>>4, tx = tid&15;
  int qrow = nt*64 + r;
  bool qv = qrow < NN;
  const float* Ap = qb + (size_t)qrow*NO3 + c4;
  float rcode[4];
#pragma unroll
  for (int i=0;i<4;i++){
    int n = nt*64 + (ty<<2) + i;
    rcode[i] = (n < NN) ? fminf(fmaxf(rintf(rowmax[(size_t)bh*NN + n]/s)+z, 0.f), 255.f) : 0.f;
  }
  float num[4][4] = {};
  float den[4] = {};
  for (int mt=0; mt<4; mt++){
    int krow = mt*64 + r;
    bool kv = krow < NN;
    const float* Bp = kb + (size_t)krow*NO3 + c4;
    float acc[4][4] = {};
    for (int kk=0; kk<ND; kk+=16){
      float4 a  = qv ? *(const float4*)(Ap+kk) : make_float4(0.f,0.f,0.f,0.f);
      float4 bb = kv ? *(const float4*)(Bp+kk) : make_float4(0.f,0.f,0.f,0.f);
      __syncthreads();   // also protects Es/Vs reads of previous iteration
      Qs[c4+0][r]=a.x;  Qs[c4+1][r]=a.y;  Qs[c4+2][r]=a.z;  Qs[c4+3][r]=a.w;
      Ks[c4+0][r]=bb.x; Ks[c4+1][r]=bb.y; Ks[c4+2][r]=bb.z; Ks[c4+3][r]=bb.w;
      __syncthreads();
#pragma unroll
      for (int k=0;k<16;k++){
        float av[4], bv[4];
        *(float4*)av = *(const float4*)&Qs[k][ty<<2];
        *(float4*)bv = *(const float4*)&Ks[k][tx<<2];
#pragma unroll
        for (int i=0;i<4;i++)
#pragma unroll
          for (int j=0;j<4;j++) acc[i][j] = fmaf(av[i], bv[j], acc[i][j]);
      }
    }
    // e values -> Es  (dead rows produce finite garbage, never read cross-row)
#pragma unroll
    for (int i=0;i<4;i++){
#pragma unroll
      for (int j=0;j<4;j++){
        int m = mt*64 + (tx<<2) + j;
        float e = 0.f;
        if (m < NN){
          float sc = acc[i][j]*0.125f;
          float code = fminf(fmaxf(rintf(sc/s)+z, 0.f), 255.f);
          float xx = fmaxf(code - rcode[i], x030);   // x_int - rowmax (z cancels)
          float qe = floorf(xx / x0);
          float rr = xx - x0*qe;
          float p = rr*(rr + bint) + cint;
          e = scalbnf(p, -(int)qe) * as2;
          den[i] += e;
        }
        Es[(ty<<2)+i][(tx<<2)+j] = e;
      }
    }
    // stage V chunk (rows mt*64..+63 of this head)
    int vr0 = tid>>4, vc = (tid&15)<<2;
#pragma unroll
    for (int q4=0;q4<4;q4++){
      int vrow = mt*64 + vr0 + q4*16;
      float4 vv = (vrow < NN) ? *(const float4*)(vb + (size_t)vrow*NO3 + vc)
                              : make_float4(0.f,0.f,0.f,0.f);
      *(float4*)&Vs[vr0 + q4*16][vc] = vv;
    }
    __syncthreads();
    // num += Es(64xm) * Vs(mx64)
#pragma unroll 4
    for (int m=0;m<64;m++){
      float4 vv = *(const float4*)&Vs[m][tx<<2];
#pragma unroll
      for (int i=0;i<4;i++){
        float ee = Es[(ty<<2)+i][m];
        num[i][0] = fmaf(ee, vv.x, num[i][0]);
        num[i][1] = fmaf(ee, vv.y, num[i][1]);
        num[i][2] = fmaf(ee, vv.z, num[i][2]);
        num[i][3] = fmaf(ee, vv.w, num[i][3]);
      }
    }
  }
  // den: sum across tx group
#pragma unroll
  for (int i=0;i<4;i++){
    float v = den[i];
#pragma unroll
    for (int o=1;o<16;o<<=1) v += __shfl_xor(v,o,64);
    den[i] = v;
  }
  float gmn = 3.4e38f, gmx = -3.4e38f;
#pragma unroll
  for (int i=0;i<4;i++){
    int n = nt*64 + (ty<<2) + i;
    if (n < NN){
      float* op = outp + ((size_t)b*NN + n)*NC + h*ND + (tx<<2);
#pragma unroll
      for (int j=0;j<4;j++){
        float o = num[i][j] / den[i];
        op[j] = o;
        gmn = fminf(gmn, o); gmx = fmaxf(gmx, o);
      }
    }
  }
  gmn = wmin(gmn); gmx = wmax(gmx);
  int wv = tid>>6;
  if ((tid&63)==0){ redn[wv]=gmn; redx[wv]=gmx; }
  __syncthreads();
  if (tid==0){
    float mn = fminf(fminf(redn[0],redn[1]), fminf(redn[2],redn[3]));
    float mx = fmaxf(fmaxf(redx[0],redx[1]), fmaxf(redx[2],redx[3]));
    atomicMin(&oslot[0], fenc(mn));
    atomicMax(&oslot[1], fenc(mx));
  }
}

__global__ __launch_bounds__(256) void k_fq_inplace(float* x, long n4, const u32* __restrict__ slots){
  float mn = fdec(slots[0]), mx = fdec(slots[1]);
  float s = fmaxf((mx-mn)/255.0f, 1e-8f);
  float z = rintf(-mn/s);
  for (long i = (long)blockIdx.x*blockDim.x + threadIdx.x; i < n4; i += (long)gridDim.x*blockDim.x){
    float4 v = ((float4*)x)[i];
    v.x = fqdq(v.x,s,z); v.y = fqdq(v.y,s,z); v.z = fqdq(v.z,s,z); v.w = fqdq(v.w,s,z);
    ((float4*)x)[i] = v;
  }
}

extern "C" void kernel_launch(void* const* d_in, const int* in_sizes, int n_in,
                              void* d_out, int out_size, void* d_ws, size_t ws_size,
                              hipStream_t stream) {
  (void)in_sizes; (void)n_in; (void)out_size; (void)ws_size;
  const float* x      = (const float*)d_in[0];
  const float* w_qkv  = (const float*)d_in[1];
  const float* b_qkv  = (const float*)d_in[2];
  const float* w_proj = (const float*)d_in[3];
  const float* b_proj = (const float*)d_in[4];
  float* out = (float*)d_out;

  u32* slots    = (u32*)d_ws;
  float* wq1    = (float*)((char*)d_ws + 256);      // 1,769,472 f
  float* wq2    = wq1 + (size_t)NO3*NC;             //   589,824 f
  float* rowmax = wq2 + (size_t)NC*NC;              //   151,296 f
  float* qkv    = rowmax + (size_t)NBH*NN;          // 29,048,832 f
  float* outpv  = qkv + (size_t)NM*NO3;             // 9,682,944 f
  // total = 41,242,368 floats + 256 B  ~= 157.3 MB

  k_init<<<1, 64, 0, stream>>>(slots);
  k_wquant<<<NO3 + NC, 256, 0, stream>>>(w_qkv, w_proj, wq1, wq2);
  k_gemm_nt<false,1><<<dim3(NO3/256, NM/64), 256, 0, stream>>>(x, wq1, b_qkv, qkv, NC, NO3, nullptr, slots);
  k_dequant_qkv<<<2048, 256, 0, stream>>>(qkv, slots);
  k_qk_rowmax<<<dim3(4, NBH), 256, 0, stream>>>(qkv, rowmax, slots);
  k_attn_pv<<<dim3(4, NBH), 256, 0, stream>>>(qkv, rowmax, slots, outpv, slots + 8);
  k_gemm_nt<true,2><<<dim3(NC/256, NM/64), 256, 0, stream>>>(outpv, wq2, b_proj, out, NC, NC, slots + 8, slots + 10);
  k_fq_inplace<<<1024, 256, 0, stream>>>(out, (long)NM*NC/4, slots + 10);
}

// Round 4
// 717.437 us; speedup vs baseline: 1.7305x; 1.7305x over previous
//
#include <hip/hip_runtime.h>

// ---------------------------------------------------------------------------
// QAttn (I-BERT int8 fake-quant attention), B=64 N=197 C=768 H=12 D=64
// Round 4: both GEMMs moved to bf16 MFMA (16x16x32), exploiting quantization:
//   - weight codes (ints <=128) are EXACT in bf16 -> B operand, scale in epilogue
//   - GEMM2 A operand = fq codes (ints <=255) -> exact bf16, single MFMA pass
//   - GEMM1 A operand = raw f32 x -> hi/lo bf16 split (2 MFMAs, ~1e-4 rel err)
// Pipeline: init -> wquant(codes+scales) -> mfma_gemm<0> (qkv, fused slice
// min/max) -> dequant_qkv -> qk_rowmax -> attn_pv -> mfma_gemm<1> (out, fused
// min/max) -> fq_inplace.  Attention section unchanged from round 3 (passed).
// Workspace 163.8 MB (< round-3's 164.9 MB which fit).
// ---------------------------------------------------------------------------

#define NB 64
#define NN 197
#define NC 768
#define NH 12
#define ND 64
#define NO3 2304
#define NBH (NB*NH)      // 768
#define NM (NB*NN)       // 12608

typedef unsigned int u32;
typedef unsigned short u16;
typedef short bf16x8 __attribute__((ext_vector_type(8)));
typedef float f32x4 __attribute__((ext_vector_type(4)));

__device__ __forceinline__ u32 fenc(float f){
  u32 u = __float_as_uint(f);
  return (u & 0x80000000u) ? ~u : (u | 0x80000000u);
}
__device__ __forceinline__ float fdec(u32 e){
  return (e & 0x80000000u) ? __uint_as_float(e ^ 0x80000000u) : __uint_as_float(~e);
}
__device__ __forceinline__ float wmin(float v){
#pragma unroll
  for (int o=32;o>0;o>>=1) v = fminf(v, __shfl_xor(v,o,64));
  return v;
}
__device__ __forceinline__ float wmax(float v){
#pragma unroll
  for (int o=32;o>0;o>>=1) v = fmaxf(v, __shfl_xor(v,o,64));
  return v;
}
__device__ __forceinline__ float fqdq(float x, float s, float z){
  float q = rintf(x/s) + z;
  q = fminf(fmaxf(q, 0.f), 255.f);
  return (q - z) * s;
}
// manual bf16 RNE (finite inputs only) — avoids header-type friction
__device__ __forceinline__ u16 tobf(float f){
  u32 u = __float_as_uint(f);
  return (u16)((u + 0x7fffu + ((u >> 16) & 1u)) >> 16);
}
__device__ __forceinline__ float frombf(u16 u){
  return __uint_as_float(((u32)u) << 16);
}

// slots[12]: {q_mn,mx, k_mn,mx, v_mn,mx, attn_mn,mx, out_mn,mx, out2_mn,mx}
__global__ void k_init(u32* slots){
  int t = threadIdx.x;
  if (t < 12) slots[t] = (t & 1) ? 0u : 0xFFFFFFFFu;
}

// per-row symmetric int8 weight quant -> bf16 integer codes + f32 row scale
__global__ __launch_bounds__(256) void k_wquant(const float* __restrict__ wqkv,
    const float* __restrict__ wproj, u16* __restrict__ B1, float* __restrict__ s1,
    u16* __restrict__ B2, float* __restrict__ s2){
  int row = blockIdx.x;
  const float* src; u16* dst; float* sd;
  if (row < NO3){ src = wqkv + (size_t)row*NC; dst = B1 + (size_t)row*NC; sd = s1 + row; }
  else { int r2 = row - NO3; src = wproj + (size_t)r2*NC; dst = B2 + (size_t)r2*NC; sd = s2 + r2; }
  int t = threadIdx.x;
  float w0 = src[t], w1 = src[t+256], w2 = src[t+512];
  float am = fmaxf(fabsf(w0), fmaxf(fabsf(w1), fabsf(w2)));
  __shared__ float red[4];
  am = wmax(am);
  if ((t&63)==0) red[t>>6] = am;
  __syncthreads();
  am = fmaxf(fmaxf(red[0],red[1]), fmaxf(red[2],red[3]));
  float s = fmaxf(am / 127.0f, 1e-8f);
  dst[t]     = tobf(fminf(fmaxf(rintf(w0/s), -128.f), 127.f));
  dst[t+256] = tobf(fminf(fmaxf(rintf(w1/s), -128.f), 127.f));
  dst[t+512] = tobf(fminf(fmaxf(rintf(w2/s), -128.f), 127.f));
  if (t==0) *sd = s;
}

// ---------------------------------------------------------------------------
// MFMA GEMM: C[m,o] = (A-ish[m,:] . codes[o,:]) * scale(o) + bias[o]
// 128x128 tile, BK=32, 256 thr = 4 waves (2x2), wave does 64x64 = 4x4 frags
// of v_mfma_f32_16x16x32_bf16. Reg-staged LDS, rows padded to 40 shorts.
// MODE 0 (GEMM1): A = f32 x; staged as hi/lo bf16 split (2 MFMA sets).
//                 epilogue: acc*s1[o]+bias; fused per-slice min/max (slice=bx/6)
// MODE 1 (GEMM2): A = f32 outpv, quantized to integer (code-z) bf16 in staging
//                 using qslot; epilogue: acc*sA*s2[o]+bias; fused global min/max
// ---------------------------------------------------------------------------
template<int MODE>
__global__ __launch_bounds__(256) void k_mfma_gemm(const float* __restrict__ A,
    const u16* __restrict__ Bw, const float* __restrict__ sw,
    const float* __restrict__ bias, float* __restrict__ C, int K, int O,
    const u32* __restrict__ qslot, u32* oslot)
{
  __shared__ u16 Ah[128*40];
  __shared__ u16 Al[(MODE==0) ? 128*40 : 8];
  __shared__ u16 Bs[128*40];
  __shared__ float redn[4], redx[4];

  int tid = threadIdx.x;
  int l = tid & 63, w = tid >> 6;
  long m0 = (long)blockIdx.y * 128;
  long o0 = (long)blockIdx.x * 128;
  int srow = tid >> 1;             // staging row 0..127
  int scol = (tid & 1) << 4;       // staging col 0 or 16
  bool arow_ok = (m0 + srow) < NM;
  const float* Ap = A + (arow_ok ? (m0 + srow) : 0) * (long)K + scol;
  const u16*  Bp = Bw + (o0 + srow) * (long)K + scol;

  float sA = 1.f, zA = 0.f;
  if constexpr (MODE==1){
    float mn = fdec(qslot[0]), mx = fdec(qslot[1]);
    sA = fmaxf((mx-mn)/255.0f, 1e-8f);
    zA = rintf(-mn/sA);
  }

  int wm = (w>>1)*64, wn = (w&1)*64;   // wave's 64x64 sub-tile
  int fr = l & 15;                     // fragment row/col within 16
  int fc = (l>>4)*8;                   // fragment K-chunk (8 contiguous)

  f32x4 acc[4][4];
#pragma unroll
  for (int mi=0;mi<4;mi++)
#pragma unroll
    for (int ni=0;ni<4;ni++)
#pragma unroll
      for (int j=0;j<4;j++) acc[mi][ni][j] = 0.f;

  for (int k0=0; k0<K; k0+=32){
    float4 av0, av1, av2, av3;
    if (arow_ok){
      av0 = *(const float4*)(Ap + k0);
      av1 = *(const float4*)(Ap + k0 + 4);
      av2 = *(const float4*)(Ap + k0 + 8);
      av3 = *(const float4*)(Ap + k0 + 12);
    } else {
      av0 = av1 = av2 = av3 = make_float4(0.f,0.f,0.f,0.f);
    }
    uint4 bv0 = *(const uint4*)(Bp + k0);
    uint4 bv1 = *(const uint4*)(Bp + k0 + 8);

    float xs[16];
    *(float4*)&xs[0] = av0; *(float4*)&xs[4]  = av1;
    *(float4*)&xs[8] = av2; *(float4*)&xs[12] = av3;
    bf16x8 h0, h1, lo0, lo1;
    if constexpr (MODE==0){
#pragma unroll
      for (int j=0;j<8;j++){
        u16 h = tobf(xs[j]);
        h0[j]  = (short)h;
        lo0[j] = (short)tobf(xs[j] - frombf(h));
      }
#pragma unroll
      for (int j=0;j<8;j++){
        u16 h = tobf(xs[8+j]);
        h1[j]  = (short)h;
        lo1[j] = (short)tobf(xs[8+j] - frombf(h));
      }
    } else {
#pragma unroll
      for (int j=0;j<16;j++){
        float q = fminf(fmaxf(rintf(xs[j]/sA)+zA, 0.f), 255.f) - zA;  // exact int
        if (j<8) h0[j] = (short)tobf(q); else h1[j-8] = (short)tobf(q);
      }
    }

    __syncthreads();   // previous iteration's fragment reads complete
    *(bf16x8*)&Ah[srow*40 + scol]     = h0;
    *(bf16x8*)&Ah[srow*40 + scol + 8] = h1;
    if constexpr (MODE==0){
      *(bf16x8*)&Al[srow*40 + scol]     = lo0;
      *(bf16x8*)&Al[srow*40 + scol + 8] = lo1;
    }
    *(bf16x8*)&Bs[srow*40 + scol]     = *(bf16x8*)&bv0;
    *(bf16x8*)&Bs[srow*40 + scol + 8] = *(bf16x8*)&bv1;
    __syncthreads();

    bf16x8 bfr[4];
#pragma unroll
    for (int ni=0;ni<4;ni++)
      bfr[ni] = *(const bf16x8*)&Bs[(wn + ni*16 + fr)*40 + fc];
#pragma unroll
    for (int mi=0;mi<4;mi++){
      bf16x8 ah = *(const bf16x8*)&Ah[(wm + mi*16 + fr)*40 + fc];
#pragma unroll
      for (int ni=0;ni<4;ni++)
        acc[mi][ni] = __builtin_amdgcn_mfma_f32_16x16x32_bf16(ah, bfr[ni], acc[mi][ni], 0, 0, 0);
    }
    if constexpr (MODE==0){
#pragma unroll
      for (int mi=0;mi<4;mi++){
        bf16x8 al = *(const bf16x8*)&Al[(wm + mi*16 + fr)*40 + fc];
#pragma unroll
        for (int ni=0;ni<4;ni++)
          acc[mi][ni] = __builtin_amdgcn_mfma_f32_16x16x32_bf16(al, bfr[ni], acc[mi][ni], 0, 0, 0);
      }
    }
  }

  // epilogue: scale + bias, guarded store, fused min/max
  float cmn = 3.4e38f, cmx = -3.4e38f;
#pragma unroll
  for (int ni=0;ni<4;ni++){
    long col = o0 + wn + ni*16 + fr;
    float sc = sw[col];
    if constexpr (MODE==1) sc *= sA;
    float bb = bias[col];
#pragma unroll
    for (int mi=0;mi<4;mi++){
      long row0 = m0 + wm + mi*16 + (l>>4)*4;
#pragma unroll
      for (int j=0;j<4;j++){
        long rr = row0 + j;
        if (rr < NM){
          float v = acc[mi][ni][j] * sc + bb;
          C[rr*(long)O + col] = v;
          cmn = fminf(cmn, v); cmx = fmaxf(cmx, v);
        }
      }
    }
  }
  cmn = wmin(cmn); cmx = wmax(cmx);
  if (l==0){ redn[w] = cmn; redx[w] = cmx; }
  __syncthreads();
  if (tid==0){
    float mn = fminf(fminf(redn[0],redn[1]), fminf(redn[2],redn[3]));
    float mx = fmaxf(fmaxf(redx[0],redx[1]), fmaxf(redx[2],redx[3]));
    int sb = (MODE==0) ? 2*(int)(blockIdx.x/6) : 0;   // 768/128 = 6 tiles/slice
    atomicMin(&oslot[sb],   fenc(mn));
    atomicMax(&oslot[sb+1], fenc(mx));
  }
}

// in-place: qkv -> slice_fq(global_fq(qkv)); slice ranges via monotonicity.
__global__ __launch_bounds__(256) void k_dequant_qkv(float* qkv, const u32* __restrict__ slots){
  float mnr0=fdec(slots[0]), mxr0=fdec(slots[1]);
  float mnr1=fdec(slots[2]), mxr1=fdec(slots[3]);
  float mnr2=fdec(slots[4]), mxr2=fdec(slots[5]);
  float mn1 = fminf(mnr0, fminf(mnr1, mnr2));
  float mx1 = fmaxf(mxr0, fmaxf(mxr1, mxr2));
  float s1 = fmaxf((mx1-mn1)/255.0f, 1e-8f);
  float z1 = rintf(-mn1/s1);
  float a0 = fqdq(mnr0,s1,z1), b0 = fqdq(mxr0,s1,z1);
  float a1 = fqdq(mnr1,s1,z1), b1 = fqdq(mxr1,s1,z1);
  float a2 = fqdq(mnr2,s1,z1), b2 = fqdq(mxr2,s1,z1);
  float s20 = fmaxf((b0-a0)/255.0f, 1e-8f), z20 = rintf(-a0/s20);
  float s21 = fmaxf((b1-a1)/255.0f, 1e-8f), z21 = rintf(-a1/s21);
  float s22 = fmaxf((b2-a2)/255.0f, 1e-8f), z22 = rintf(-a2/s22);
  const long n4 = (long)NM*NO3/4;
  for (long i = (long)blockIdx.x*blockDim.x + threadIdx.x; i < n4; i += (long)gridDim.x*blockDim.x){
    float4 v = ((float4*)qkv)[i];
    int sl = (int)((i*4) % NO3) / NC;
    float s2, z2;
    if (sl==0){ s2=s20; z2=z20; } else if (sl==1){ s2=s21; z2=z21; } else { s2=s22; z2=z22; }
    v.x = fqdq(fqdq(v.x,s1,z1), s2, z2);
    v.y = fqdq(fqdq(v.y,s1,z1), s2, z2);
    v.z = fqdq(fqdq(v.z,s1,z1), s2, z2);
    v.w = fqdq(fqdq(v.w,s1,z1), s2, z2);
    ((float4*)qkv)[i] = v;
  }
}

// Pass 1: raw-score global min/max (slots 6,7) + per-row raw max
__global__ __launch_bounds__(256) void k_qk_rowmax(const float* __restrict__ qkv,
    float* __restrict__ rowmax, u32* slots){
  __shared__ float Qs[16][64];
  __shared__ float Ks[16][64];
  __shared__ float redn[4], redx[4];
  int bh = blockIdx.y; int b = bh/NH, h = bh - b*NH;
  int nt = blockIdx.x;
  const float* qb = qkv + (size_t)b*NN*NO3 + h*ND;
  const float* kb = qb + NC;
  int tid = threadIdx.x;
  int r = tid>>2, c4 = (tid&3)<<2;
  int ty = tid>>4, tx = tid&15;
  int qrow = nt*64 + r;
  bool qv = qrow < NN;
  const float* Ap = qb + (size_t)qrow*NO3 + c4;
  float rmax[4] = {-3.4e38f,-3.4e38f,-3.4e38f,-3.4e38f};
  float gmn = 3.4e38f, gmx = -3.4e38f;
  for (int mt=0; mt<4; mt++){
    int krow = mt*64 + r;
    bool kv = krow < NN;
    const float* Bp = kb + (size_t)krow*NO3 + c4;
    float acc[4][4] = {};
    for (int kk=0; kk<ND; kk+=16){
      float4 a  = qv ? *(const float4*)(Ap+kk) : make_float4(0.f,0.f,0.f,0.f);
      float4 bb = kv ? *(const float4*)(Bp+kk) : make_float4(0.f,0.f,0.f,0.f);
      __syncthreads();
      Qs[c4+0][r]=a.x;  Qs[c4+1][r]=a.y;  Qs[c4+2][r]=a.z;  Qs[c4+3][r]=a.w;
      Ks[c4+0][r]=bb.x; Ks[c4+1][r]=bb.y; Ks[c4+2][r]=bb.z; Ks[c4+3][r]=bb.w;
      __syncthreads();
#pragma unroll
      for (int k=0;k<16;k++){
        float av[4], bv[4];
        *(float4*)av = *(const float4*)&Qs[k][ty<<2];
        *(float4*)bv = *(const float4*)&Ks[k][tx<<2];
#pragma unroll
        for (int i=0;i<4;i++)
#pragma unroll
          for (int j=0;j<4;j++) acc[i][j] = fmaf(av[i], bv[j], acc[i][j]);
      }
    }
#pragma unroll
    for (int i=0;i<4;i++){
      int n = nt*64 + (ty<<2) + i;
      if (n < NN){
#pragma unroll
        for (int j=0;j<4;j++){
          int m = mt*64 + (tx<<2) + j;
          if (m < NN){
            float sc = acc[i][j]*0.125f;
            rmax[i] = fmaxf(rmax[i], sc);
            gmn = fminf(gmn, sc); gmx = fmaxf(gmx, sc);
          }
        }
      }
    }
  }
#pragma unroll
  for (int i=0;i<4;i++){
    float v = rmax[i];
#pragma unroll
    for (int o=1;o<16;o<<=1) v = fmaxf(v, __shfl_xor(v,o,64));
    rmax[i] = v;
  }
  if (tx==0){
#pragma unroll
    for (int i=0;i<4;i++){
      int n = nt*64 + (ty<<2) + i;
      if (n < NN) rowmax[(size_t)bh*NN + n] = rmax[i];
    }
  }
  gmn = wmin(gmn); gmx = wmax(gmx);
  int wv = tid>>6;
  if ((tid&63)==0){ redn[wv]=gmn; redx[wv]=gmx; }
  __syncthreads();
  if (tid==0){
    float mn = fminf(fminf(redn[0],redn[1]), fminf(redn[2],redn[3]));
    float mx = fmaxf(fmaxf(redx[0],redx[1]), fmaxf(redx[2],redx[3]));
    atomicMin(&slots[6], fenc(mn));
    atomicMax(&slots[7], fenc(mx));
  }
}

// Pass 2: recompute scores, I-BERT exp, out = (e.V)/(sum e); fused out min/max
__global__ __launch_bounds__(256) void k_attn_pv(const float* __restrict__ qkv,
    const float* __restrict__ rowmax, const u32* __restrict__ slots,
    float* __restrict__ outp, u32* oslot){
  __shared__ float Qs[16][64];
  __shared__ float Ks[16][64];
  __shared__ float Es[64][68];
  __shared__ float Vs[64][68];
  __shared__ float redn[4], redx[4];
  float mnA = fdec(slots[6]), mxA = fdec(slots[7]);
  float s = fmaxf((mxA-mnA)/255.0f, 1e-8f);
  float z = rintf(-mnA/s);
  float x0 = floorf(-0.6931471805599453f / s);
  float ba = (float)(0.96963238/0.35815147);
  float ca = (float)(1.0/0.35815147);
  float bint = floorf(ba/s);
  float cint = floorf(ca/(s*s));
  float as2 = (0.35815147f*s)*s;
  float x030 = 30.f*x0;
  int bh = blockIdx.y; int b = bh/NH, h = bh - b*NH;
  int nt = blockIdx.x;
  const float* qb = qkv + (size_t)b*NN*NO3 + h*ND;
  const float* kb = qb + NC;
  const float* vb = qkv + (size_t)b*NN*NO3 + 2*NC + h*ND;
  int tid = threadIdx.x;
  int r = tid>>2, c4 = (tid&3)<<2;
  int ty = tid>>4, tx = tid&15;
  int qrow = nt*64 + r;
  bool qv = qrow < NN;
  const float* Ap = qb + (size_t)qrow*NO3 + c4;
  float rcode[4];
#pragma unroll
  for (int i=0;i<4;i++){
    int n = nt*64 + (ty<<2) + i;
    rcode[i] = (n < NN) ? fminf(fmaxf(rintf(rowmax[(size_t)bh*NN + n]/s)+z, 0.f), 255.f) : 0.f;
  }
  float num[4][4] = {};
  float den[4] = {};
  for (int mt=0; mt<4; mt++){
    int krow = mt*64 + r;
    bool kv = krow < NN;
    const float* Bp = kb + (size_t)krow*NO3 + c4;
    float acc[4][4] = {};
    for (int kk=0; kk<ND; kk+=16){
      float4 a  = qv ? *(const float4*)(Ap+kk) : make_float4(0.f,0.f,0.f,0.f);
      float4 bb = kv ? *(const float4*)(Bp+kk) : make_float4(0.f,0.f,0.f,0.f);
      __syncthreads();
      Qs[c4+0][r]=a.x;  Qs[c4+1][r]=a.y;  Qs[c4+2][r]=a.z;  Qs[c4+3][r]=a.w;
      Ks[c4+0][r]=bb.x; Ks[c4+1][r]=bb.y; Ks[c4+2][r]=bb.z; Ks[c4+3][r]=bb.w;
      __syncthreads();
#pragma unroll
      for (int k=0;k<16;k++){
        float av[4], bv[4];
        *(float4*)av = *(const float4*)&Qs[k][ty<<2];
        *(float4*)bv = *(const float4*)&Ks[k][tx<<2];
#pragma unroll
        for (int i=0;i<4;i++)
#pragma unroll
          for (int j=0;j<4;j++) acc[i][j] = fmaf(av[i], bv[j], acc[i][j]);
      }
    }
#pragma unroll
    for (int i=0;i<4;i++){
#pragma unroll
      for (int j=0;j<4;j++){
        int m = mt*64 + (tx<<2) + j;
        float e = 0.f;
        if (m < NN){
          float sc = acc[i][j]*0.125f;
          float code = fminf(fmaxf(rintf(sc/s)+z, 0.f), 255.f);
          float xx = fmaxf(code - rcode[i], x030);
          float qe = floorf(xx / x0);
          float rr = xx - x0*qe;
          float p = rr*(rr + bint) + cint;
          e = scalbnf(p, -(int)qe) * as2;
          den[i] += e;
        }
        Es[(ty<<2)+i][(tx<<2)+j] = e;
      }
    }
    int vr0 = tid>>4, vc = (tid&15)<<2;
#pragma unroll
    for (int q4=0;q4<4;q4++){
      int vrow = mt*64 + vr0 + q4*16;
      float4 vv = (vrow < NN) ? *(const float4*)(vb + (size_t)vrow*NO3 + vc)
                              : make_float4(0.f,0.f,0.f,0.f);
      *(float4*)&Vs[vr0 + q4*16][vc] = vv;
    }
    __syncthreads();
#pragma unroll 4
    for (int m=0;m<64;m++){
      float4 vv = *(const float4*)&Vs[m][tx<<2];
#pragma unroll
      for (int i=0;i<4;i++){
        float ee = Es[(ty<<2)+i][m];
        num[i][0] = fmaf(ee, vv.x, num[i][0]);
        num[i][1] = fmaf(ee, vv.y, num[i][1]);
        num[i][2] = fmaf(ee, vv.z, num[i][2]);
        num[i][3] = fmaf(ee, vv.w, num[i][3]);
      }
    }
  }
#pragma unroll
  for (int i=0;i<4;i++){
    float v = den[i];
#pragma unroll
    for (int o=1;o<16;o<<=1) v += __shfl_xor(v,o,64);
    den[i] = v;
  }
  float gmn = 3.4e38f, gmx = -3.4e38f;
#pragma unroll
  for (int i=0;i<4;i++){
    int n = nt*64 + (ty<<2) + i;
    if (n < NN){
      float* op = outp + ((size_t)b*NN + n)*NC + h*ND + (tx<<2);
#pragma unroll
      for (int j=0;j<4;j++){
        float o = num[i][j] / den[i];
        op[j] = o;
        gmn = fminf(gmn, o); gmx = fmaxf(gmx, o);
      }
    }
  }
  gmn = wmin(gmn); gmx = wmax(gmx);
  int wv = tid>>6;
  if ((tid&63)==0){ redn[wv]=gmn; redx[wv]=gmx; }
  __syncthreads();
  if (tid==0){
    float mn = fminf(fminf(redn[0],redn[1]), fminf(redn[2],redn[3]));
    float mx = fmaxf(fmaxf(redx[0],redx[1]), fmaxf(redx[2],redx[3]));
    atomicMin(&oslot[0], fenc(mn));
    atomicMax(&oslot[1], fenc(mx));
  }
}

__global__ __launch_bounds__(256) void k_fq_inplace(float* x, long n4, const u32* __restrict__ slots){
  float mn = fdec(slots[0]), mx = fdec(slots[1]);
  float s = fmaxf((mx-mn)/255.0f, 1e-8f);
  float z = rintf(-mn/s);
  for (long i = (long)blockIdx.x*blockDim.x + threadIdx.x; i < n4; i += (long)gridDim.x*blockDim.x){
    float4 v = ((float4*)x)[i];
    v.x = fqdq(v.x,s,z); v.y = fqdq(v.y,s,z); v.z = fqdq(v.z,s,z); v.w = fqdq(v.w,s,z);
    ((float4*)x)[i] = v;
  }
}

extern "C" void kernel_launch(void* const* d_in, const int* in_sizes, int n_in,
                              void* d_out, int out_size, void* d_ws, size_t ws_size,
                              hipStream_t stream) {
  (void)in_sizes; (void)n_in; (void)out_size; (void)ws_size;
  const float* x      = (const float*)d_in[0];
  const float* w_qkv  = (const float*)d_in[1];
  const float* b_qkv  = (const float*)d_in[2];
  const float* w_proj = (const float*)d_in[3];
  const float* b_proj = (const float*)d_in[4];
  float* out = (float*)d_out;

  u32*   slots  = (u32*)d_ws;
  u16*   B1     = (u16*)((char*)d_ws + 256);        // 2304*768 bf16 codes
  u16*   B2     = B1 + (size_t)NO3*NC;              //  768*768 bf16 codes
  float* s1     = (float*)(B2 + (size_t)NC*NC);     // 2304
  float* s2     = s1 + NO3;                         //  768
  float* rowmax = s2 + NC;                          // 151296
  float* qkv    = rowmax + (size_t)NBH*NN;          // 12608*2304 f32
  float* outpv  = qkv + (size_t)NM*NO3;             // 12608*768  f32
  // total ~163.8 MB (< 164.9 MB which fit in round 3)

  k_init<<<1, 64, 0, stream>>>(slots);
  k_wquant<<<NO3 + NC, 256, 0, stream>>>(w_qkv, w_proj, B1, s1, B2, s2);
  k_mfma_gemm<0><<<dim3(NO3/128, 99), 256, 0, stream>>>(x, B1, s1, b_qkv, qkv, NC, NO3, nullptr, slots);
  k_dequant_qkv<<<2048, 256, 0, stream>>>(qkv, slots);
  k_qk_rowmax<<<dim3(4, NBH), 256, 0, stream>>>(qkv, rowmax, slots);
  k_attn_pv<<<dim3(4, NBH), 256, 0, stream>>>(qkv, rowmax, slots, outpv, slots + 8);
  k_mfma_gemm<1><<<dim3(NC/128, 99), 256, 0, stream>>>(outpv, B2, s2, b_proj, out, NC, NC, slots + 8, slots + 10);
  k_fq_inplace<<<1024, 256, 0, stream>>>(out, (long)NM*NC/4, slots + 10);
}

// Round 5
// 575.858 us; speedup vs baseline: 2.1560x; 1.2459x over previous
//
#include <hip/hip_runtime.h>

// ---------------------------------------------------------------------------
// QAttn (I-BERT int8 fake-quant attention), B=64 N=197 C=768 H=12 D=64
// Round 5: attention moved to MFMA on bf16 INTEGER CODES.
//   After double fake-quant, q/k/v = scale * int with |int|<=255 -> exact bf16.
//   QK^T: 0.125*sq*sk * mfma(iq,ik)  (integer sum < 2^24 -> bit-exact f32)
//   PV:   e split hi/lo bf16 (A) x V codes (B, in-LDS transpose), den via shfl
// Pipeline: init -> wquant -> mfma_gemm<0>(qkv raw + slice minmax) ->
//   transcode(raw->codes, replaces dequant) -> attn<1> (rowmax + score minmax)
//   -> attn<2> (PV -> outpv + minmax) -> mfma_gemm<1> -> fq_inplace.
// outpv ALIASES the dead qkv-raw region: ws ~= 180 MB.
// ---------------------------------------------------------------------------

#define NB 64
#define NN 197
#define NC 768
#define NH 12
#define ND 64
#define NO3 2304
#define NBH (NB*NH)      // 768
#define NM (NB*NN)       // 12608

typedef unsigned int u32;
typedef unsigned short u16;
typedef unsigned long long u64;
typedef short bf16x8 __attribute__((ext_vector_type(8)));
typedef float f32x4 __attribute__((ext_vector_type(4)));

__device__ __forceinline__ u32 fenc(float f){
  u32 u = __float_as_uint(f);
  return (u & 0x80000000u) ? ~u : (u | 0x80000000u);
}
__device__ __forceinline__ float fdec(u32 e){
  return (e & 0x80000000u) ? __uint_as_float(e ^ 0x80000000u) : __uint_as_float(~e);
}
__device__ __forceinline__ float wmin(float v){
#pragma unroll
  for (int o=32;o>0;o>>=1) v = fminf(v, __shfl_xor(v,o,64));
  return v;
}
__device__ __forceinline__ float wmax(float v){
#pragma unroll
  for (int o=32;o>0;o>>=1) v = fmaxf(v, __shfl_xor(v,o,64));
  return v;
}
__device__ __forceinline__ float fqdq(float x, float s, float z){
  float q = rintf(x/s) + z;
  q = fminf(fmaxf(q, 0.f), 255.f);
  return (q - z) * s;
}
__device__ __forceinline__ u16 tobf(float f){
  u32 u = __float_as_uint(f);
  return (u16)((u + 0x7fffu + ((u >> 16) & 1u)) >> 16);
}
__device__ __forceinline__ float frombf(u16 u){
  return __uint_as_float(((u32)u) << 16);
}

// derive qkv slice quant params from slots[0..5] (identical math everywhere)
__device__ __forceinline__ void qkv_scales(const u32* slots, float* s2, float* z2,
                                           float* s1o, float* z1o){
  float mnr0=fdec(slots[0]), mxr0=fdec(slots[1]);
  float mnr1=fdec(slots[2]), mxr1=fdec(slots[3]);
  float mnr2=fdec(slots[4]), mxr2=fdec(slots[5]);
  float mn1 = fminf(mnr0, fminf(mnr1, mnr2));
  float mx1 = fmaxf(mxr0, fmaxf(mxr1, mxr2));
  float s1 = fmaxf((mx1-mn1)/255.0f, 1e-8f);
  float z1 = rintf(-mn1/s1);
  float a0 = fqdq(mnr0,s1,z1), b0 = fqdq(mxr0,s1,z1);
  float a1 = fqdq(mnr1,s1,z1), b1 = fqdq(mxr1,s1,z1);
  float a2 = fqdq(mnr2,s1,z1), b2 = fqdq(mxr2,s1,z1);
  s2[0] = fmaxf((b0-a0)/255.0f,1e-8f); z2[0] = rintf(-a0/s2[0]);
  s2[1] = fmaxf((b1-a1)/255.0f,1e-8f); z2[1] = rintf(-a1/s2[1]);
  s2[2] = fmaxf((b2-a2)/255.0f,1e-8f); z2[2] = rintf(-a2/s2[2]);
  *s1o = s1; *z1o = z1;
}

// slots[12]: {q_mn,mx, k_mn,mx, v_mn,mx, attn_mn,mx, out_mn,mx, out2_mn,mx}
__global__ void k_init(u32* slots){
  int t = threadIdx.x;
  if (t < 12) slots[t] = (t & 1) ? 0u : 0xFFFFFFFFu;
}

// per-row symmetric int8 weight quant -> bf16 integer codes + f32 row scale
__global__ __launch_bounds__(256) void k_wquant(const float* __restrict__ wqkv,
    const float* __restrict__ wproj, u16* __restrict__ B1, float* __restrict__ s1,
    u16* __restrict__ B2, float* __restrict__ s2){
  int row = blockIdx.x;
  const float* src; u16* dst; float* sd;
  if (row < NO3){ src = wqkv + (size_t)row*NC; dst = B1 + (size_t)row*NC; sd = s1 + row; }
  else { int r2 = row - NO3; src = wproj + (size_t)r2*NC; dst = B2 + (size_t)r2*NC; sd = s2 + r2; }
  int t = threadIdx.x;
  float w0 = src[t], w1 = src[t+256], w2 = src[t+512];
  float am = fmaxf(fabsf(w0), fmaxf(fabsf(w1), fabsf(w2)));
  __shared__ float red[4];
  am = wmax(am);
  if ((t&63)==0) red[t>>6] = am;
  __syncthreads();
  am = fmaxf(fmaxf(red[0],red[1]), fmaxf(red[2],red[3]));
  float s = fmaxf(am / 127.0f, 1e-8f);
  dst[t]     = tobf(fminf(fmaxf(rintf(w0/s), -128.f), 127.f));
  dst[t+256] = tobf(fminf(fmaxf(rintf(w1/s), -128.f), 127.f));
  dst[t+512] = tobf(fminf(fmaxf(rintf(w2/s), -128.f), 127.f));
  if (t==0) *sd = s;
}

// MFMA GEMM (unchanged from round 4): 128x128 tile, BK=32, 4 waves 2x2.
template<int MODE>
__global__ __launch_bounds__(256) void k_mfma_gemm(const float* __restrict__ A,
    const u16* __restrict__ Bw, const float* __restrict__ sw,
    const float* __restrict__ bias, float* __restrict__ C, int K, int O,
    const u32* __restrict__ qslot, u32* oslot)
{
  __shared__ u16 Ah[128*40];
  __shared__ u16 Al[(MODE==0) ? 128*40 : 8];
  __shared__ u16 Bs[128*40];
  __shared__ float redn[4], redx[4];

  int tid = threadIdx.x;
  int l = tid & 63, w = tid >> 6;
  long m0 = (long)blockIdx.y * 128;
  long o0 = (long)blockIdx.x * 128;
  int srow = tid >> 1;
  int scol = (tid & 1) << 4;
  bool arow_ok = (m0 + srow) < NM;
  const float* Ap = A + (arow_ok ? (m0 + srow) : 0) * (long)K + scol;
  const u16*  Bp = Bw + (o0 + srow) * (long)K + scol;

  float sA = 1.f, zA = 0.f;
  if constexpr (MODE==1){
    float mn = fdec(qslot[0]), mx = fdec(qslot[1]);
    sA = fmaxf((mx-mn)/255.0f, 1e-8f);
    zA = rintf(-mn/sA);
  }

  int wm = (w>>1)*64, wn = (w&1)*64;
  int fr = l & 15;
  int fc = (l>>4)*8;

  f32x4 acc[4][4];
#pragma unroll
  for (int mi=0;mi<4;mi++)
#pragma unroll
    for (int ni=0;ni<4;ni++)
#pragma unroll
      for (int j=0;j<4;j++) acc[mi][ni][j] = 0.f;

  for (int k0=0; k0<K; k0+=32){
    float4 av0, av1, av2, av3;
    if (arow_ok){
      av0 = *(const float4*)(Ap + k0);
      av1 = *(const float4*)(Ap + k0 + 4);
      av2 = *(const float4*)(Ap + k0 + 8);
      av3 = *(const float4*)(Ap + k0 + 12);
    } else {
      av0 = av1 = av2 = av3 = make_float4(0.f,0.f,0.f,0.f);
    }
    uint4 bv0 = *(const uint4*)(Bp + k0);
    uint4 bv1 = *(const uint4*)(Bp + k0 + 8);

    float xs[16];
    *(float4*)&xs[0] = av0; *(float4*)&xs[4]  = av1;
    *(float4*)&xs[8] = av2; *(float4*)&xs[12] = av3;
    bf16x8 h0, h1, lo0, lo1;
    if constexpr (MODE==0){
#pragma unroll
      for (int j=0;j<8;j++){
        u16 h = tobf(xs[j]);
        h0[j]  = (short)h;
        lo0[j] = (short)tobf(xs[j] - frombf(h));
      }
#pragma unroll
      for (int j=0;j<8;j++){
        u16 h = tobf(xs[8+j]);
        h1[j]  = (short)h;
        lo1[j] = (short)tobf(xs[8+j] - frombf(h));
      }
    } else {
#pragma unroll
      for (int j=0;j<16;j++){
        float q = fminf(fmaxf(rintf(xs[j]/sA)+zA, 0.f), 255.f) - zA;
        if (j<8) h0[j] = (short)tobf(q); else h1[j-8] = (short)tobf(q);
      }
    }

    __syncthreads();
    *(bf16x8*)&Ah[srow*40 + scol]     = h0;
    *(bf16x8*)&Ah[srow*40 + scol + 8] = h1;
    if constexpr (MODE==0){
      *(bf16x8*)&Al[srow*40 + scol]     = lo0;
      *(bf16x8*)&Al[srow*40 + scol + 8] = lo1;
    }
    *(bf16x8*)&Bs[srow*40 + scol]     = *(bf16x8*)&bv0;
    *(bf16x8*)&Bs[srow*40 + scol + 8] = *(bf16x8*)&bv1;
    __syncthreads();

    bf16x8 bfr[4];
#pragma unroll
    for (int ni=0;ni<4;ni++)
      bfr[ni] = *(const bf16x8*)&Bs[(wn + ni*16 + fr)*40 + fc];
#pragma unroll
    for (int mi=0;mi<4;mi++){
      bf16x8 ah = *(const bf16x8*)&Ah[(wm + mi*16 + fr)*40 + fc];
#pragma unroll
      for (int ni=0;ni<4;ni++)
        acc[mi][ni] = __builtin_amdgcn_mfma_f32_16x16x32_bf16(ah, bfr[ni], acc[mi][ni], 0, 0, 0);
    }
    if constexpr (MODE==0){
#pragma unroll
      for (int mi=0;mi<4;mi++){
        bf16x8 al = *(const bf16x8*)&Al[(wm + mi*16 + fr)*40 + fc];
#pragma unroll
        for (int ni=0;ni<4;ni++)
          acc[mi][ni] = __builtin_amdgcn_mfma_f32_16x16x32_bf16(al, bfr[ni], acc[mi][ni], 0, 0, 0);
      }
    }
  }

  float cmn = 3.4e38f, cmx = -3.4e38f;
#pragma unroll
  for (int ni=0;ni<4;ni++){
    long col = o0 + wn + ni*16 + fr;
    float sc = sw[col];
    if constexpr (MODE==1) sc *= sA;
    float bb = bias[col];
#pragma unroll
    for (int mi=0;mi<4;mi++){
      long row0 = m0 + wm + mi*16 + (l>>4)*4;
#pragma unroll
      for (int j=0;j<4;j++){
        long rr = row0 + j;
        if (rr < NM){
          float v = acc[mi][ni][j] * sc + bb;
          C[rr*(long)O + col] = v;
          cmn = fminf(cmn, v); cmx = fmaxf(cmx, v);
        }
      }
    }
  }
  cmn = wmin(cmn); cmx = wmax(cmx);
  if (l==0){ redn[w] = cmn; redx[w] = cmx; }
  __syncthreads();
  if (tid==0){
    float mn = fminf(fminf(redn[0],redn[1]), fminf(redn[2],redn[3]));
    float mx = fmaxf(fmaxf(redx[0],redx[1]), fmaxf(redx[2],redx[3]));
    int sb = (MODE==0) ? 2*(int)(blockIdx.x/6) : 0;
    atomicMin(&oslot[sb],   fenc(mn));
    atomicMax(&oslot[sb+1], fenc(mx));
  }
}

// raw qkv f32 -> per-head bf16 integer codes [sl][bh][n][d]
__global__ __launch_bounds__(256) void k_transcode(const float* __restrict__ qkv,
    u16* __restrict__ codes, const u32* __restrict__ slots){
  float s2[3], z2[3], s1g, z1g;
  qkv_scales(slots, s2, z2, &s1g, &z1g);
  const u32 total = 3u*NBH*NN*16u;
  for (u32 i4 = blockIdx.x*256u + threadIdx.x; i4 < total; i4 += gridDim.x*256u){
    u32 d4 = i4 & 15u;
    u32 t1 = i4 >> 4;
    u32 n  = t1 % NN;
    u32 t2 = t1 / NN;
    u32 bh = t2 % NBH;
    u32 sl = t2 / NBH;
    u32 b = bh / NH, h = bh % NH;
    float4 v = *(const float4*)(qkv + ((size_t)b*NN + n)*NO3 + sl*NC + h*ND + d4*4u);
    float ss = s2[sl], zz = z2[sl];
    u64 c0 = (u64)tobf(fminf(fmaxf(rintf(fqdq(v.x,s1g,z1g)/ss)+zz,0.f),255.f) - zz);
    u64 c1 = (u64)tobf(fminf(fmaxf(rintf(fqdq(v.y,s1g,z1g)/ss)+zz,0.f),255.f) - zz);
    u64 c2 = (u64)tobf(fminf(fmaxf(rintf(fqdq(v.z,s1g,z1g)/ss)+zz,0.f),255.f) - zz);
    u64 c3 = (u64)tobf(fminf(fmaxf(rintf(fqdq(v.w,s1g,z1g)/ss)+zz,0.f),255.f) - zz);
    *(u64*)(codes + ((size_t)sl*NBH*NN + (size_t)bh*NN + n)*ND + d4*4u) =
        c0 | (c1<<16) | (c2<<32) | (c3<<48);
  }
}

// ---------------------------------------------------------------------------
// MFMA attention. grid (4, 768); 4 waves; wave w owns 16 q-rows.
// PASS 1: score global min/max (atomics slots[6,7]) + per-row raw max.
// PASS 2: recompute scores (bitwise identical), I-BERT e, PV via hi/lo bf16
//         MFMA, out=sv*num/den -> outp; fused out min/max -> slots[8,9].
// ---------------------------------------------------------------------------
template<int PASS>
__global__ __launch_bounds__(256) void k_attn(const u16* __restrict__ codes,
    float* __restrict__ rowmax, u32* slots, float* __restrict__ outp){
  __shared__ u16 Ks[64*72];
  __shared__ u16 Vt[(PASS==2)?64*72:8];
  __shared__ u16 EsH[(PASS==2)?64*72:8];
  __shared__ u16 EsL[(PASS==2)?64*72:8];
  __shared__ float redn[4], redx[4];

  const u16* qc = codes;
  const u16* kc = codes + (size_t)NBH*NN*ND;
  const u16* vc = codes + 2*(size_t)NBH*NN*ND;

  float s2[3], z2[3], s1g, z1g;
  qkv_scales(slots, s2, z2, &s1g, &z1g);
  float ss = 0.125f * s2[0] * s2[1];
  float sv = s2[2];

  float s=1.f, z=0.f, x0=-1.f, bint=0.f, cint=0.f, as2=0.f, x030=0.f;
  if constexpr (PASS==2){
    float mnA = fdec(slots[6]), mxA = fdec(slots[7]);
    s = fmaxf((mxA-mnA)/255.0f, 1e-8f);
    z = rintf(-mnA/s);
    x0 = floorf(-0.6931471805599453f / s);
    bint = floorf((float)(0.96963238/0.35815147) / s);
    cint = floorf((float)(1.0/0.35815147) / (s*s));
    as2 = (0.35815147f*s)*s;
    x030 = 30.f*x0;
  }

  int tid = threadIdx.x;
  int l = tid & 63, w = tid >> 6;
  int bh = blockIdx.y, nt = blockIdx.x;
  int lr = l & 15, lk = l >> 4;

  int qrow = nt*64 + w*16 + lr;
  bf16x8 aq0 = {}, aq1 = {};
  if (qrow < NN){
    const u16* qp = qc + ((size_t)bh*NN + qrow)*ND + lk*8;
    aq0 = *(const bf16x8*)qp;
    aq1 = *(const bf16x8*)(qp + 32);
  }

  int qr[4];
#pragma unroll
  for (int j=0;j<4;j++) qr[j] = nt*64 + w*16 + lk*4 + j;

  float rcode[4] = {0.f,0.f,0.f,0.f};
  if constexpr (PASS==2){
#pragma unroll
    for (int j=0;j<4;j++)
      if (qr[j] < NN)
        rcode[j] = fminf(fmaxf(rintf(rowmax[(size_t)bh*NN + qr[j]]/s)+z,0.f),255.f);
  }

  float gmn = 3.4e38f, gmx = -3.4e38f;
  float rmx[4] = {-3.4e38f,-3.4e38f,-3.4e38f,-3.4e38f};
  float den[4] = {0.f,0.f,0.f,0.f};
  f32x4 num[4];
#pragma unroll
  for (int dt=0;dt<4;dt++)
#pragma unroll
    for (int j=0;j<4;j++) num[dt][j] = 0.f;

  for (int mt=0; mt<4; mt++){
    __syncthreads();   // prev chunk's LDS reads complete
#pragma unroll
    for (int rep=0; rep<2; rep++){
      int task = tid + rep*256;
      int row = task >> 3, dc = task & 7;
      int grow = mt*64 + row;
      bf16x8 kv8 = {};
      if (grow < NN) kv8 = *(const bf16x8*)(kc + ((size_t)bh*NN + grow)*ND + dc*8);
      *(bf16x8*)&Ks[row*72 + dc*8] = kv8;
      if constexpr (PASS==2){
        bf16x8 vv8 = {};
        if (grow < NN) vv8 = *(const bf16x8*)(vc + ((size_t)bh*NN + grow)*ND + dc*8);
#pragma unroll
        for (int jj=0;jj<8;jj++) Vt[(dc*8+jj)*72 + row] = (u16)vv8[jj];
      }
    }
    __syncthreads();

    f32x4 sca[4];
#pragma unroll
    for (int ct=0;ct<4;ct++)
#pragma unroll
      for (int j=0;j<4;j++) sca[ct][j] = 0.f;
#pragma unroll
    for (int ct=0;ct<4;ct++){
      bf16x8 bk0 = *(const bf16x8*)&Ks[(ct*16 + lr)*72 + lk*8];
      bf16x8 bk1 = *(const bf16x8*)&Ks[(ct*16 + lr)*72 + 32 + lk*8];
      sca[ct] = __builtin_amdgcn_mfma_f32_16x16x32_bf16(aq0, bk0, sca[ct], 0,0,0);
      sca[ct] = __builtin_amdgcn_mfma_f32_16x16x32_bf16(aq1, bk1, sca[ct], 0,0,0);
    }

    if constexpr (PASS==1){
#pragma unroll
      for (int ct=0;ct<4;ct++){
        int m = mt*64 + ct*16 + lr;
        bool mv = m < NN;
#pragma unroll
        for (int j=0;j<4;j++){
          float sc = sca[ct][j] * ss;
          if (mv && qr[j] < NN){
            gmn = fminf(gmn, sc); gmx = fmaxf(gmx, sc);
            rmx[j] = fmaxf(rmx[j], sc);
          }
        }
      }
    } else {
#pragma unroll
      for (int ct=0;ct<4;ct++){
        int m = mt*64 + ct*16 + lr;
        bool mv = m < NN;
#pragma unroll
        for (int j=0;j<4;j++){
          float e = 0.f;
          if (mv && qr[j] < NN){
            float sc = sca[ct][j] * ss;
            float code = fminf(fmaxf(rintf(sc/s)+z, 0.f), 255.f);
            float xx = fmaxf(code - rcode[j], x030);
            float qe = floorf(xx / x0);
            float rr = xx - x0*qe;
            float p = rr*(rr + bint) + cint;
            e = scalbnf(p, -(int)qe) * as2;
            den[j] += e;
          }
          u16 eh = tobf(e);
          int ea = (w*16 + lk*4 + j)*72 + ct*16 + lr;
          EsH[ea] = eh;
          EsL[ea] = tobf(e - frombf(eh));
        }
      }
      __syncthreads();   // Es (and Vt) visible to all lanes
#pragma unroll
      for (int ks=0; ks<2; ks++){
        bf16x8 ahh = *(const bf16x8*)&EsH[(w*16 + lr)*72 + ks*32 + lk*8];
        bf16x8 ahl = *(const bf16x8*)&EsL[(w*16 + lr)*72 + ks*32 + lk*8];
#pragma unroll
        for (int dt=0; dt<4; dt++){
          bf16x8 bv = *(const bf16x8*)&Vt[(dt*16 + lr)*72 + ks*32 + lk*8];
          num[dt] = __builtin_amdgcn_mfma_f32_16x16x32_bf16(ahh, bv, num[dt], 0,0,0);
          num[dt] = __builtin_amdgcn_mfma_f32_16x16x32_bf16(ahl, bv, num[dt], 0,0,0);
        }
      }
    }
  }

  if constexpr (PASS==1){
#pragma unroll
    for (int j=0;j<4;j++){
#pragma unroll
      for (int o=1;o<16;o<<=1) rmx[j] = fmaxf(rmx[j], __shfl_xor(rmx[j], o, 64));
    }
    if (lr == 0){
#pragma unroll
      for (int j=0;j<4;j++)
        if (qr[j] < NN) rowmax[(size_t)bh*NN + qr[j]] = rmx[j];
    }
    gmn = wmin(gmn); gmx = wmax(gmx);
    if (l==0){ redn[w]=gmn; redx[w]=gmx; }
    __syncthreads();
    if (tid==0){
      float mn = fminf(fminf(redn[0],redn[1]), fminf(redn[2],redn[3]));
      float mx = fmaxf(fmaxf(redx[0],redx[1]), fmaxf(redx[2],redx[3]));
      atomicMin(&slots[6], fenc(mn));
      atomicMax(&slots[7], fenc(mx));
    }
  } else {
#pragma unroll
    for (int j=0;j<4;j++){
#pragma unroll
      for (int o=1;o<16;o<<=1) den[j] += __shfl_xor(den[j], o, 64);
    }
    int b = bh/NH, h = bh - b*NH;
    float gmn2 = 3.4e38f, gmx2 = -3.4e38f;
#pragma unroll
    for (int dt=0;dt<4;dt++){
#pragma unroll
      for (int j=0;j<4;j++){
        if (qr[j] < NN){
          float oo = num[dt][j] * sv / den[j];
          outp[((size_t)b*NN + qr[j])*NC + h*ND + dt*16 + lr] = oo;
          gmn2 = fminf(gmn2, oo); gmx2 = fmaxf(gmx2, oo);
        }
      }
    }
    gmn2 = wmin(gmn2); gmx2 = wmax(gmx2);
    if (l==0){ redn[w]=gmn2; redx[w]=gmx2; }
    __syncthreads();
    if (tid==0){
      float mn = fminf(fminf(redn[0],redn[1]), fminf(redn[2],redn[3]));
      float mx = fmaxf(fmaxf(redx[0],redx[1]), fmaxf(redx[2],redx[3]));
      atomicMin(&slots[8], fenc(mn));
      atomicMax(&slots[9], fenc(mx));
    }
  }
}

__global__ __launch_bounds__(256) void k_fq_inplace(float* x, long n4, const u32* __restrict__ slots){
  float mn = fdec(slots[0]), mx = fdec(slots[1]);
  float s = fmaxf((mx-mn)/255.0f, 1e-8f);
  float z = rintf(-mn/s);
  for (long i = (long)blockIdx.x*blockDim.x + threadIdx.x; i < n4; i += (long)gridDim.x*blockDim.x){
    float4 v = ((float4*)x)[i];
    v.x = fqdq(v.x,s,z); v.y = fqdq(v.y,s,z); v.z = fqdq(v.z,s,z); v.w = fqdq(v.w,s,z);
    ((float4*)x)[i] = v;
  }
}

extern "C" void kernel_launch(void* const* d_in, const int* in_sizes, int n_in,
                              void* d_out, int out_size, void* d_ws, size_t ws_size,
                              hipStream_t stream) {
  (void)in_sizes; (void)n_in; (void)out_size; (void)ws_size;
  const float* x      = (const float*)d_in[0];
  const float* w_qkv  = (const float*)d_in[1];
  const float* b_qkv  = (const float*)d_in[2];
  const float* w_proj = (const float*)d_in[3];
  const float* b_proj = (const float*)d_in[4];
  float* out = (float*)d_out;

  u32*   slots  = (u32*)d_ws;
  u16*   B1     = (u16*)((char*)d_ws + 256);        // 2304*768 u16
  u16*   B2     = B1 + (size_t)NO3*NC;              //  768*768 u16
  float* s1     = (float*)(B2 + (size_t)NC*NC);     // 2304
  float* s2     = s1 + NO3;                         //  768
  float* rowmax = s2 + NC;                          // 768*197
  float* qkv    = rowmax + (size_t)NBH*NN;          // 12608*2304 f32 (116.2 MB)
  u16*   codes  = (u16*)(qkv + (size_t)NM*NO3);     // 3*768*197*64 u16 (58.1 MB)
  float* outpv  = qkv;                              // ALIAS: qkv raw dead after transcode
  // total ~179.8 MB

  k_init<<<1, 64, 0, stream>>>(slots);
  k_wquant<<<NO3 + NC, 256, 0, stream>>>(w_qkv, w_proj, B1, s1, B2, s2);
  k_mfma_gemm<0><<<dim3(NO3/128, 99), 256, 0, stream>>>(x, B1, s1, b_qkv, qkv, NC, NO3, nullptr, slots);
  k_transcode<<<2048, 256, 0, stream>>>(qkv, codes, slots);
  k_attn<1><<<dim3(4, NBH), 256, 0, stream>>>(codes, rowmax, slots, nullptr);
  k_attn<2><<<dim3(4, NBH), 256, 0, stream>>>(codes, rowmax, slots, outpv);
  k_mfma_gemm<1><<<dim3(NC/128, 99), 256, 0, stream>>>(outpv, B2, s2, b_proj, out, NC, NC, slots + 8, slots + 10);
  k_fq_inplace<<<1024, 256, 0, stream>>>(out, (long)NM*NC/4, slots + 10);
}

// Round 8
// 551.329 us; speedup vs baseline: 2.2519x; 1.0445x over previous
//
#include <hip/hip_runtime.h>

// ---------------------------------------------------------------------------
// QAttn (I-BERT int8 fake-quant attention), B=64 N=197 C=768 H=12 D=64
// Round 6 (2nd resubmit; broker timeouts): GEMMs -> m97-style global_load_lds
// bf16 MFMA kernel.
//   GEMM1: A = xhl (hi|lo bf16 split of x, concat along K, K=1536), B wraps.
//   GEMM2: A = codes2 (fq integer codes of attn output, K=768).
//   Both: 128x128 tile, BK=64, linear LDS, 2 barriers/K-step, fused minmax.
// Attention unchanged from round 5 (integer-code MFMA).
// ws ~179.8 MB: xhl & attn-codes & codes2 share one 58.1 MB region (disjoint
// lifetimes); outpv aliases dead qkv raw.
// ---------------------------------------------------------------------------

#define NB 64
#define NN 197
#define NC 768
#define NH 12
#define ND 64
#define NO3 2304
#define NBH (NB*NH)      // 768
#define NM (NB*NN)       // 12608

typedef unsigned int u32;
typedef unsigned short u16;
typedef unsigned long long u64;
typedef short bf16x8 __attribute__((ext_vector_type(8)));
typedef float f32x4 __attribute__((ext_vector_type(4)));

__device__ __forceinline__ u32 fenc(float f){
  u32 u = __float_as_uint(f);
  return (u & 0x80000000u) ? ~u : (u | 0x80000000u);
}
__device__ __forceinline__ float fdec(u32 e){
  return (e & 0x80000000u) ? __uint_as_float(e ^ 0x80000000u) : __uint_as_float(~e);
}
__device__ __forceinline__ float wmin(float v){
#pragma unroll
  for (int o=32;o>0;o>>=1) v = fminf(v, __shfl_xor(v,o,64));
  return v;
}
__device__ __forceinline__ float wmax(float v){
#pragma unroll
  for (int o=32;o>0;o>>=1) v = fmaxf(v, __shfl_xor(v,o,64));
  return v;
}
__device__ __forceinline__ float fqdq(float x, float s, float z){
  float q = rintf(x/s) + z;
  q = fminf(fmaxf(q, 0.f), 255.f);
  return (q - z) * s;
}
__device__ __forceinline__ u16 tobf(float f){
  u32 u = __float_as_uint(f);
  return (u16)((u + 0x7fffu + ((u >> 16) & 1u)) >> 16);
}
__device__ __forceinline__ float frombf(u16 u){
  return __uint_as_float(((u32)u) << 16);
}
// async global->LDS, 16B per lane (dest must be wave-uniform base + lane*16)
__device__ __forceinline__ void gload16(const void* g, void* l){
  __builtin_amdgcn_global_load_lds(
      (const __attribute__((address_space(1))) void*)g,
      (__attribute__((address_space(3))) void*)l, 16, 0, 0);
}

// derive qkv slice quant params from slots[0..5]
__device__ __forceinline__ void qkv_scales(const u32* slots, float* s2, float* z2,
                                           float* s1o, float* z1o){
  float mnr0=fdec(slots[0]), mxr0=fdec(slots[1]);
  float mnr1=fdec(slots[2]), mxr1=fdec(slots[3]);
  float mnr2=fdec(slots[4]), mxr2=fdec(slots[5]);
  float mn1 = fminf(mnr0, fminf(mnr1, mnr2));
  float mx1 = fmaxf(mxr0, fmaxf(mxr1, mxr2));
  float s1 = fmaxf((mx1-mn1)/255.0f, 1e-8f);
  float z1 = rintf(-mn1/s1);
  float a0 = fqdq(mnr0,s1,z1), b0 = fqdq(mxr0,s1,z1);
  float a1 = fqdq(mnr1,s1,z1), b1 = fqdq(mxr1,s1,z1);
  float a2 = fqdq(mnr2,s1,z1), b2 = fqdq(mxr2,s1,z1);
  s2[0] = fmaxf((b0-a0)/255.0f,1e-8f); z2[0] = rintf(-a0/s2[0]);
  s2[1] = fmaxf((b1-a1)/255.0f,1e-8f); z2[1] = rintf(-a1/s2[1]);
  s2[2] = fmaxf((b2-a2)/255.0f,1e-8f); z2[2] = rintf(-a2/s2[2]);
  *s1o = s1; *z1o = z1;
}

// slots[12]: {q_mn,mx, k_mn,mx, v_mn,mx, attn_mn,mx, out_mn,mx, out2_mn,mx}
__global__ void k_init(u32* slots){
  int t = threadIdx.x;
  if (t < 12) slots[t] = (t & 1) ? 0u : 0xFFFFFFFFu;
}

// per-row symmetric int8 weight quant -> bf16 integer codes + f32 row scale
__global__ __launch_bounds__(256) void k_wquant(const float* __restrict__ wqkv,
    const float* __restrict__ wproj, u16* __restrict__ B1, float* __restrict__ s1,
    u16* __restrict__ B2, float* __restrict__ s2){
  int row = blockIdx.x;
  const float* src; u16* dst; float* sd;
  if (row < NO3){ src = wqkv + (size_t)row*NC; dst = B1 + (size_t)row*NC; sd = s1 + row; }
  else { int r2 = row - NO3; src = wproj + (size_t)r2*NC; dst = B2 + (size_t)r2*NC; sd = s2 + r2; }
  int t = threadIdx.x;
  float w0 = src[t], w1 = src[t+256], w2 = src[t+512];
  float am = fmaxf(fabsf(w0), fmaxf(fabsf(w1), fabsf(w2)));
  __shared__ float red[4];
  am = wmax(am);
  if ((t&63)==0) red[t>>6] = am;
  __syncthreads();
  am = fmaxf(fmaxf(red[0],red[1]), fmaxf(red[2],red[3]));
  float s = fmaxf(am / 127.0f, 1e-8f);
  dst[t]     = tobf(fminf(fmaxf(rintf(w0/s), -128.f), 127.f));
  dst[t+256] = tobf(fminf(fmaxf(rintf(w1/s), -128.f), 127.f));
  dst[t+512] = tobf(fminf(fmaxf(rintf(w2/s), -128.f), 127.f));
  if (t==0) *sd = s;
}

// x f32 [M][768] -> xhl bf16 [M][1536] = hi | lo (residual) concat along K
__global__ __launch_bounds__(256) void k_xsplit(const float* __restrict__ x,
    u16* __restrict__ xhl){
  const u32 total = (u32)NM*192u;
  for (u32 i = blockIdx.x*256u + threadIdx.x; i < total; i += gridDim.x*256u){
    u32 row = i / 192u, kc = (i - row*192u)*4u;
    float4 v = *(const float4*)(x + (size_t)row*NC + kc);
    u16 h0=tobf(v.x), h1=tobf(v.y), h2=tobf(v.z), h3=tobf(v.w);
    u64 hp = (u64)h0 | ((u64)h1<<16) | ((u64)h2<<32) | ((u64)h3<<48);
    u64 lp = (u64)tobf(v.x-frombf(h0)) | ((u64)tobf(v.y-frombf(h1))<<16)
           | ((u64)tobf(v.z-frombf(h2))<<32) | ((u64)tobf(v.w-frombf(h3))<<48);
    size_t base = (size_t)row*1536 + kc;
    *(u64*)(xhl + base) = hp;
    *(u64*)(xhl + base + 768) = lp;
  }
}

// attn output f32 [M][768] -> fq integer codes (code - z, exact bf16)
__global__ __launch_bounds__(256) void k_transcode2(const float* __restrict__ p,
    u16* __restrict__ codes2, const u32* __restrict__ slots){
  float mn = fdec(slots[0]), mx = fdec(slots[1]);
  float s = fmaxf((mx-mn)/255.0f, 1e-8f);
  float z = rintf(-mn/s);
  const u32 total = (u32)NM*192u;
  for (u32 i = blockIdx.x*256u + threadIdx.x; i < total; i += gridDim.x*256u){
    u32 row = i / 192u, kc = (i - row*192u)*4u;
    float4 v = *(const float4*)(p + (size_t)row*NC + kc);
    u64 c0 = (u64)tobf(fminf(fmaxf(rintf(v.x/s)+z,0.f),255.f) - z);
    u64 c1 = (u64)tobf(fminf(fmaxf(rintf(v.y/s)+z,0.f),255.f) - z);
    u64 c2 = (u64)tobf(fminf(fmaxf(rintf(v.z/s)+z,0.f),255.f) - z);
    u64 c3 = (u64)tobf(fminf(fmaxf(rintf(v.w/s)+z,0.f),255.f) - z);
    *(u64*)(codes2 + (size_t)row*NC + kc) = c0 | (c1<<16) | (c2<<32) | (c3<<48);
  }
}

// ---------------------------------------------------------------------------
// m97-style bf16 GEMM: C[m,o] = (sum_k A[m,k]*B[o,k mod 768]) * sc(o) + bias[o]
// 128x128 tile, BK=64, 4 waves (2x2, 64x64 each), global_load_lds staging.
// MODE 0: GEMM1 (KA=1536 hi|lo), sc=sw[o]; slice minmax -> oslot[2*(bx/6)]
// MODE 1: GEMM2 (KA=768 codes),  sc=sw[o]*sA(qslot); global minmax -> oslot[0,1]
// ---------------------------------------------------------------------------
template<int MODE>
__global__ __launch_bounds__(256) void k_gemm_bf16(const u16* __restrict__ A, int KA,
    const u16* __restrict__ Bw, const float* __restrict__ sw,
    const float* __restrict__ bias, float* __restrict__ C, int O,
    const u32* __restrict__ qslot, u32* oslot)
{
  __shared__ u16 As[128*64];
  __shared__ u16 Bs[128*64];
  __shared__ float redn[4], redx[4];

  int tid = threadIdx.x;
  int l = tid & 63, w = tid >> 6;
  long m0 = (long)blockIdx.y * 128;
  long o0 = (long)blockIdx.x * 128;

  float sA = 1.f;
  if constexpr (MODE==1){
    float mn = fdec(qslot[0]), mx = fdec(qslot[1]);
    sA = fmaxf((mx-mn)/255.0f, 1e-8f);
  }

  int srow = tid >> 3;          // 0..31
  int scol = (tid & 7) * 8;     // u16 units: 0,8,...,56
  long arow[4]; const u16* bpr[4];
#pragma unroll
  for (int q=0;q<4;q++){
    long mr = m0 + srow + q*32;
    arow[q] = (mr < NM) ? mr : (long)(NM-1);   // clamp tail (rows never stored)
    bpr[q] = Bw + (size_t)(o0 + srow + q*32) * NC + scol;
  }

  int wm = (w>>1)*64, wn = (w&1)*64;
  int fr = l & 15;
  int fcb = ((l>>4)*8)*2;       // byte offset of lane's 8-elem k-chunk

  f32x4 acc[4][4];
#pragma unroll
  for (int mi=0;mi<4;mi++)
#pragma unroll
    for (int ni=0;ni<4;ni++)
#pragma unroll
      for (int j=0;j<4;j++) acc[mi][ni][j] = 0.f;

  int nkt = KA >> 6;
  for (int kt=0; kt<nkt; kt++){
    int ka0 = kt*64;
    int kb0 = (ka0 >= NC) ? (ka0 - NC) : ka0;   // B wraps for KA=1536
    __syncthreads();
#pragma unroll
    for (int q=0;q<4;q++){
      gload16(A + (size_t)arow[q]*KA + ka0 + scol, &As[(srow + q*32)*64 + scol]);
      gload16(bpr[q] + kb0,                        &Bs[(srow + q*32)*64 + scol]);
    }
    __syncthreads();
#pragma unroll
    for (int ks=0; ks<2; ks++){
      bf16x8 bfr[4];
#pragma unroll
      for (int ni=0;ni<4;ni++)
        bfr[ni] = *(const bf16x8*)((const char*)&Bs[(wn + ni*16 + fr)*64] + ks*64 + fcb);
#pragma unroll
      for (int mi=0;mi<4;mi++){
        bf16x8 af = *(const bf16x8*)((const char*)&As[(wm + mi*16 + fr)*64] + ks*64 + fcb);
#pragma unroll
        for (int ni=0;ni<4;ni++)
          acc[mi][ni] = __builtin_amdgcn_mfma_f32_16x16x32_bf16(af, bfr[ni], acc[mi][ni], 0,0,0);
      }
    }
  }

  float cmn = 3.4e38f, cmx = -3.4e38f;
#pragma unroll
  for (int ni=0;ni<4;ni++){
    long col = o0 + wn + ni*16 + fr;
    float sc = sw[col];
    if constexpr (MODE==1) sc *= sA;
    float bb = bias[col];
#pragma unroll
    for (int mi=0;mi<4;mi++){
      long row0 = m0 + wm + mi*16 + (l>>4)*4;
#pragma unroll
      for (int j=0;j<4;j++){
        long rr = row0 + j;
        if (rr < NM){
          float v = acc[mi][ni][j] * sc + bb;
          C[rr*(long)O + col] = v;
          cmn = fminf(cmn, v); cmx = fmaxf(cmx, v);
        }
      }
    }
  }
  cmn = wmin(cmn); cmx = wmax(cmx);
  if (l==0){ redn[w] = cmn; redx[w] = cmx; }
  __syncthreads();
  if (tid==0){
    float mn = fminf(fminf(redn[0],redn[1]), fminf(redn[2],redn[3]));
    float mx = fmaxf(fmaxf(redx[0],redx[1]), fmaxf(redx[2],redx[3]));
    int sb = (MODE==0) ? 2*(int)(blockIdx.x/6) : 0;
    atomicMin(&oslot[sb],   fenc(mn));
    atomicMax(&oslot[sb+1], fenc(mx));
  }
}

// raw qkv f32 -> per-head bf16 integer codes [sl][bh][n][d]
__global__ __launch_bounds__(256) void k_transcode(const float* __restrict__ qkv,
    u16* __restrict__ codes, const u32* __restrict__ slots){
  float s2[3], z2[3], s1g, z1g;
  qkv_scales(slots, s2, z2, &s1g, &z1g);
  const u32 total = 3u*NBH*NN*16u;
  for (u32 i4 = blockIdx.x*256u + threadIdx.x; i4 < total; i4 += gridDim.x*256u){
    u32 d4 = i4 & 15u;
    u32 t1 = i4 >> 4;
    u32 n  = t1 % NN;
    u32 t2 = t1 / NN;
    u32 bh = t2 % NBH;
    u32 sl = t2 / NBH;
    u32 b = bh / NH, h = bh % NH;
    float4 v = *(const float4*)(qkv + ((size_t)b*NN + n)*NO3 + sl*NC + h*ND + d4*4u);
    float ss = s2[sl], zz = z2[sl];
    u64 c0 = (u64)tobf(fminf(fmaxf(rintf(fqdq(v.x,s1g,z1g)/ss)+zz,0.f),255.f) - zz);
    u64 c1 = (u64)tobf(fminf(fmaxf(rintf(fqdq(v.y,s1g,z1g)/ss)+zz,0.f),255.f) - zz);
    u64 c2 = (u64)tobf(fminf(fmaxf(rintf(fqdq(v.z,s1g,z1g)/ss)+zz,0.f),255.f) - zz);
    u64 c3 = (u64)tobf(fminf(fmaxf(rintf(fqdq(v.w,s1g,z1g)/ss)+zz,0.f),255.f) - zz);
    *(u64*)(codes + ((size_t)sl*NBH*NN + (size_t)bh*NN + n)*ND + d4*4u) =
        c0 | (c1<<16) | (c2<<32) | (c3<<48);
  }
}

// ---------------------------------------------------------------------------
// MFMA attention (unchanged from round 5). grid (4, 768); 4 waves.
// ---------------------------------------------------------------------------
template<int PASS>
__global__ __launch_bounds__(256) void k_attn(const u16* __restrict__ codes,
    float* __restrict__ rowmax, u32* slots, float* __restrict__ outp){
  __shared__ u16 Ks[64*72];
  __shared__ u16 Vt[(PASS==2)?64*72:8];
  __shared__ u16 EsH[(PASS==2)?64*72:8];
  __shared__ u16 EsL[(PASS==2)?64*72:8];
  __shared__ float redn[4], redx[4];

  const u16* qc = codes;
  const u16* kc = codes + (size_t)NBH*NN*ND;
  const u16* vc = codes + 2*(size_t)NBH*NN*ND;

  float s2[3], z2[3], s1g, z1g;
  qkv_scales(slots, s2, z2, &s1g, &z1g);
  float ss = 0.125f * s2[0] * s2[1];
  float sv = s2[2];

  float s=1.f, z=0.f, x0=-1.f, bint=0.f, cint=0.f, as2=0.f, x030=0.f;
  if constexpr (PASS==2){
    float mnA = fdec(slots[6]), mxA = fdec(slots[7]);
    s = fmaxf((mxA-mnA)/255.0f, 1e-8f);
    z = rintf(-mnA/s);
    x0 = floorf(-0.6931471805599453f / s);
    bint = floorf((float)(0.96963238/0.35815147) / s);
    cint = floorf((float)(1.0/0.35815147) / (s*s));
    as2 = (0.35815147f*s)*s;
    x030 = 30.f*x0;
  }

  int tid = threadIdx.x;
  int l = tid & 63, w = tid >> 6;
  int bh = blockIdx.y, nt = blockIdx.x;
  int lr = l & 15, lk = l >> 4;

  int qrow = nt*64 + w*16 + lr;
  bf16x8 aq0 = {}, aq1 = {};
  if (qrow < NN){
    const u16* qp = qc + ((size_t)bh*NN + qrow)*ND + lk*8;
    aq0 = *(const bf16x8*)qp;
    aq1 = *(const bf16x8*)(qp + 32);
  }

  int qr[4];
#pragma unroll
  for (int j=0;j<4;j++) qr[j] = nt*64 + w*16 + lk*4 + j;

  float rcode[4] = {0.f,0.f,0.f,0.f};
  if constexpr (PASS==2){
#pragma unroll
    for (int j=0;j<4;j++)
      if (qr[j] < NN)
        rcode[j] = fminf(fmaxf(rintf(rowmax[(size_t)bh*NN + qr[j]]/s)+z,0.f),255.f);
  }

  float gmn = 3.4e38f, gmx = -3.4e38f;
  float rmx[4] = {-3.4e38f,-3.4e38f,-3.4e38f,-3.4e38f};
  float den[4] = {0.f,0.f,0.f,0.f};
  f32x4 num[4];
#pragma unroll
  for (int dt=0;dt<4;dt++)
#pragma unroll
    for (int j=0;j<4;j++) num[dt][j] = 0.f;

  for (int mt=0; mt<4; mt++){
    __syncthreads();
#pragma unroll
    for (int rep=0; rep<2; rep++){
      int task = tid + rep*256;
      int row = task >> 3, dc = task & 7;
      int grow = mt*64 + row;
      bf16x8 kv8 = {};
      if (grow < NN) kv8 = *(const bf16x8*)(kc + ((size_t)bh*NN + grow)*ND + dc*8);
      *(bf16x8*)&Ks[row*72 + dc*8] = kv8;
      if constexpr (PASS==2){
        bf16x8 vv8 = {};
        if (grow < NN) vv8 = *(const bf16x8*)(vc + ((size_t)bh*NN + grow)*ND + dc*8);
#pragma unroll
        for (int jj=0;jj<8;jj++) Vt[(dc*8+jj)*72 + row] = (u16)vv8[jj];
      }
    }
    __syncthreads();

    f32x4 sca[4];
#pragma unroll
    for (int ct=0;ct<4;ct++)
#pragma unroll
      for (int j=0;j<4;j++) sca[ct][j] = 0.f;
#pragma unroll
    for (int ct=0;ct<4;ct++){
      bf16x8 bk0 = *(const bf16x8*)&Ks[(ct*16 + lr)*72 + lk*8];
      bf16x8 bk1 = *(const bf16x8*)&Ks[(ct*16 + lr)*72 + 32 + lk*8];
      sca[ct] = __builtin_amdgcn_mfma_f32_16x16x32_bf16(aq0, bk0, sca[ct], 0,0,0);
      sca[ct] = __builtin_amdgcn_mfma_f32_16x16x32_bf16(aq1, bk1, sca[ct], 0,0,0);
    }

    if constexpr (PASS==1){
#pragma unroll
      for (int ct=0;ct<4;ct++){
        int m = mt*64 + ct*16 + lr;
        bool mv = m < NN;
#pragma unroll
        for (int j=0;j<4;j++){
          float sc = sca[ct][j] * ss;
          if (mv && qr[j] < NN){
            gmn = fminf(gmn, sc); gmx = fmaxf(gmx, sc);
            rmx[j] = fmaxf(rmx[j], sc);
          }
        }
      }
    } else {
#pragma unroll
      for (int ct=0;ct<4;ct++){
        int m = mt*64 + ct*16 + lr;
        bool mv = m < NN;
#pragma unroll
        for (int j=0;j<4;j++){
          float e = 0.f;
          if (mv && qr[j] < NN){
            float sc = sca[ct][j] * ss;
            float code = fminf(fmaxf(rintf(sc/s)+z, 0.f), 255.f);
            float xx = fmaxf(code - rcode[j], x030);
            float qe = floorf(xx / x0);
            float rr = xx - x0*qe;
            float p = rr*(rr + bint) + cint;
            e = scalbnf(p, -(int)qe) * as2;
            den[j] += e;
          }
          u16 eh = tobf(e);
          int ea = (w*16 + lk*4 + j)*72 + ct*16 + lr;
          EsH[ea] = eh;
          EsL[ea] = tobf(e - frombf(eh));
        }
      }
      __syncthreads();
#pragma unroll
      for (int ks=0; ks<2; ks++){
        bf16x8 ahh = *(const bf16x8*)&EsH[(w*16 + lr)*72 + ks*32 + lk*8];
        bf16x8 ahl = *(const bf16x8*)&EsL[(w*16 + lr)*72 + ks*32 + lk*8];
#pragma unroll
        for (int dt=0; dt<4; dt++){
          bf16x8 bv = *(const bf16x8*)&Vt[(dt*16 + lr)*72 + ks*32 + lk*8];
          num[dt] = __builtin_amdgcn_mfma_f32_16x16x32_bf16(ahh, bv, num[dt], 0,0,0);
          num[dt] = __builtin_amdgcn_mfma_f32_16x16x32_bf16(ahl, bv, num[dt], 0,0,0);
        }
      }
    }
  }

  if constexpr (PASS==1){
#pragma unroll
    for (int j=0;j<4;j++){
#pragma unroll
      for (int o=1;o<16;o<<=1) rmx[j] = fmaxf(rmx[j], __shfl_xor(rmx[j], o, 64));
    }
    if (lr == 0){
#pragma unroll
      for (int j=0;j<4;j++)
        if (qr[j] < NN) rowmax[(size_t)bh*NN + qr[j]] = rmx[j];
    }
    gmn = wmin(gmn); gmx = wmax(gmx);
    if (l==0){ redn[w]=gmn; redx[w]=gmx; }
    __syncthreads();
    if (tid==0){
      float mn = fminf(fminf(redn[0],redn[1]), fminf(redn[2],redn[3]));
      float mx = fmaxf(fmaxf(redx[0],redx[1]), fmaxf(redx[2],redx[3]));
      atomicMin(&slots[6], fenc(mn));
      atomicMax(&slots[7], fenc(mx));
    }
  } else {
#pragma unroll
    for (int j=0;j<4;j++){
#pragma unroll
      for (int o=1;o<16;o<<=1) den[j] += __shfl_xor(den[j], o, 64);
    }
    int b = bh/NH, h = bh - b*NH;
    float gmn2 = 3.4e38f, gmx2 = -3.4e38f;
#pragma unroll
    for (int dt=0;dt<4;dt++){
#pragma unroll
      for (int j=0;j<4;j++){
        if (qr[j] < NN){
          float oo = num[dt][j] * sv / den[j];
          outp[((size_t)b*NN + qr[j])*NC + h*ND + dt*16 + lr] = oo;
          gmn2 = fminf(gmn2, oo); gmx2 = fmaxf(gmx2, oo);
        }
      }
    }
    gmn2 = wmin(gmn2); gmx2 = wmax(gmx2);
    if (l==0){ redn[w]=gmn2; redx[w]=gmx2; }
    __syncthreads();
    if (tid==0){
      float mn = fminf(fminf(redn[0],redn[1]), fminf(redn[2],redn[3]));
      float mx = fmaxf(fmaxf(redx[0],redx[1]), fmaxf(redx[2],redx[3]));
      atomicMin(&slots[8], fenc(mn));
      atomicMax(&slots[9], fenc(mx));
    }
  }
}

__global__ __launch_bounds__(256) void k_fq_inplace(float* x, long n4, const u32* __restrict__ slots){
  float mn = fdec(slots[0]), mx = fdec(slots[1]);
  float s = fmaxf((mx-mn)/255.0f, 1e-8f);
  float z = rintf(-mn/s);
  for (long i = (long)blockIdx.x*blockDim.x + threadIdx.x; i < n4; i += (long)gridDim.x*blockDim.x){
    float4 v = ((float4*)x)[i];
    v.x = fqdq(v.x,s,z); v.y = fqdq(v.y,s,z); v.z = fqdq(v.z,s,z); v.w = fqdq(v.w,s,z);
    ((float4*)x)[i] = v;
  }
}

extern "C" void kernel_launch(void* const* d_in, const int* in_sizes, int n_in,
                              void* d_out, int out_size, void* d_ws, size_t ws_size,
                              hipStream_t stream) {
  (void)in_sizes; (void)n_in; (void)out_size; (void)ws_size;
  const float* x      = (const float*)d_in[0];
  const float* w_qkv  = (const float*)d_in[1];
  const float* b_qkv  = (const float*)d_in[2];
  const float* w_proj = (const float*)d_in[3];
  const float* b_proj = (const float*)d_in[4];
  float* out = (float*)d_out;

  u32*   slots  = (u32*)d_ws;
  u16*   B1     = (u16*)((char*)d_ws + 256);        // 2304*768 u16
  u16*   B2     = B1 + (size_t)NO3*NC;              //  768*768 u16
  float* s1     = (float*)(B2 + (size_t)NC*NC);     // 2304
  float* s2     = s1 + NO3;                         //  768
  float* rowmax = s2 + NC;                          // 768*197
  float* qkv    = rowmax + (size_t)NBH*NN;          // 12608*2304 f32 (116.2 MB)
  u16*   codesR = (u16*)(qkv + (size_t)NM*NO3);     // 58.1 MB shared region:
  u16*   xhl    = codesR;                           //   [M][1536] bf16 (38.7 MB), dies at transcode
  u16*   codes  = codesR;                           //   attn codes (58.1 MB), dies at transcode2
  u16*   codes2 = codesR;                           //   [M][768] bf16 (19.4 MB)
  float* outpv  = qkv;                              // ALIAS: qkv raw dead after transcode

  k_init<<<1, 64, 0, stream>>>(slots);
  k_wquant<<<NO3 + NC, 256, 0, stream>>>(w_qkv, w_proj, B1, s1, B2, s2);
  k_xsplit<<<1024, 256, 0, stream>>>(x, xhl);
  k_gemm_bf16<0><<<dim3(NO3/128, 99), 256, 0, stream>>>(xhl, 1536, B1, s1, b_qkv, qkv, NO3, nullptr, slots);
  k_transcode<<<2048, 256, 0, stream>>>(qkv, codes, slots);
  k_attn<1><<<dim3(4, NBH), 256, 0, stream>>>(codes, rowmax, slots, nullptr);
  k_attn<2><<<dim3(4, NBH), 256, 0, stream>>>(codes, rowmax, slots, outpv);
  k_transcode2<<<1024, 256, 0, stream>>>(outpv, codes2, slots + 8);
  k_gemm_bf16<1><<<dim3(NC/128, 99), 256, 0, stream>>>(codes2, 768, B2, s2, b_proj, out, NC, slots + 8, slots + 10);
  k_fq_inplace<<<1024, 256, 0, stream>>>(out, (long)NM*NC/4, slots + 10);
}